// Round 2
// baseline (900.118 us; speedup 1.0000x reference)
//
#include <hip/hip_runtime.h>
#include <math.h>

#define N_NODES 65536
#define N_EDGES 524288
#define N_GRAPHS 1024
#define H 128
#define R_RES 512
#define NH 4
#define HD 32
#define D_IN 7
#define EPS 1e-5f

// ---------------- CSR build ----------------
__global__ __launch_bounds__(256) void k_count(const int* __restrict__ dst, int* __restrict__ cnt, int E){
  int e = blockIdx.x*256 + threadIdx.x;
  if (e < E) atomicAdd(&cnt[dst[e]], 1);
}

__global__ __launch_bounds__(1024) void k_scan(const int* __restrict__ cnt, int* __restrict__ csr_off,
                                               int* __restrict__ cursor, float* __restrict__ dinv){
  __shared__ int part[1024];
  int t = threadIdx.x;
  int base = t*64;
  int s = 0;
  for (int j=0;j<64;j++) s += cnt[base+j];
  part[t] = s;
  __syncthreads();
  for (int off=1; off<1024; off<<=1){
    int v = (t >= off) ? part[t-off] : 0;
    __syncthreads();
    part[t] += v;
    __syncthreads();
  }
  int run = (t == 0) ? 0 : part[t-1];
  for (int j=0;j<64;j++){
    int i = base+j;
    int c = cnt[i];
    csr_off[i] = run;
    cursor[i] = run;
    dinv[i] = rsqrtf(1.0f + (float)c);   // deg = 1 + in-degree
    run += c;
  }
  if (t == 0) csr_off[N_NODES] = N_EDGES;
}

__global__ __launch_bounds__(256) void k_fill(const int* __restrict__ src, const int* __restrict__ dst,
      const float* __restrict__ dinv, int* __restrict__ cursor,
      int* __restrict__ csr_src, float* __restrict__ csr_w, int E){
  int e = blockIdx.x*256 + threadIdx.x;
  if (e >= E) return;
  int s = src[e], d = dst[e];
  int p = atomicAdd(&cursor[d], 1);
  csr_src[p] = s;
  csr_w[p] = dinv[s]*dinv[d];            // enorm
}

// ---------------- generic fp32 GEMM: C[N,128] = A[N,K] @ B (+bias) ----------------
// transB==0: B is [K,128] row-major.  transB==1: B(k,c) = Bsrc[c*K + k] (i.e. X @ W^T).
__global__ __launch_bounds__(256,2) void k_gemm(const float* __restrict__ A, const float* __restrict__ B,
      const float* __restrict__ bias, float* __restrict__ C, int K, int transB){
  __shared__ float Bs[128][132];   // full B; padded so staging writes are cheap, reads 16B-aligned
  __shared__ float As[16][128];    // per-k-tile, [k][row] -> conflict-free reads
  int tid = threadIdx.x;
  long rowBase = (long)blockIdx.x * 128;

  if (!transB){
    for (int idx = tid; idx < 128*128; idx += 256){
      int k = idx >> 7, c = idx & 127;
      Bs[k][c] = (k < K) ? B[(long)k*128 + c] : 0.0f;
    }
  } else {
    for (int idx = tid; idx < 128*128; idx += 256){
      int c = idx >> 7, k = idx & 127;
      Bs[k][c] = (k < K) ? B[(long)c*K + k] : 0.0f;
    }
  }

  float acc[8][8];
  #pragma unroll
  for (int i=0;i<8;i++){
    #pragma unroll
    for (int j=0;j<8;j++) acc[i][j] = 0.0f;
  }

  int rg = tid >> 4, cg = tid & 15;
  int r0 = rg*8, c0 = cg*8;
  int srow = tid >> 1, skoff = (tid & 1)*8;
  const bool fast = ((K & 15) == 0);

  for (int k0 = 0; k0 < K; k0 += 16){
    __syncthreads();
    const float* ap = A + (rowBase + srow)*K + k0 + skoff;
    if (fast){
      float4 v0 = *(const float4*)(ap);
      float4 v1 = *(const float4*)(ap + 4);
      As[skoff+0][srow] = v0.x; As[skoff+1][srow] = v0.y;
      As[skoff+2][srow] = v0.z; As[skoff+3][srow] = v0.w;
      As[skoff+4][srow] = v1.x; As[skoff+5][srow] = v1.y;
      As[skoff+6][srow] = v1.z; As[skoff+7][srow] = v1.w;
    } else {
      #pragma unroll
      for (int j=0;j<8;j++){
        int kk = k0 + skoff + j;
        As[skoff+j][srow] = (kk < K) ? ap[j] : 0.0f;
      }
    }
    __syncthreads();
    #pragma unroll
    for (int k=0;k<16;k++){
      float4 a0 = *(const float4*)(&As[k][r0]);
      float4 a1 = *(const float4*)(&As[k][r0+4]);
      float4 b0 = *(const float4*)(&Bs[k0+k][c0]);      // FIX: Bs holds full B -> index k0+k
      float4 b1 = *(const float4*)(&Bs[k0+k][c0+4]);
      float a[8] = {a0.x,a0.y,a0.z,a0.w,a1.x,a1.y,a1.z,a1.w};
      float b[8] = {b0.x,b0.y,b0.z,b0.w,b1.x,b1.y,b1.z,b1.w};
      #pragma unroll
      for (int i=0;i<8;i++){
        #pragma unroll
        for (int j=0;j<8;j++)
          acc[i][j] = fmaf(a[i], b[j], acc[i][j]);
      }
    }
  }

  #pragma unroll
  for (int i=0;i<8;i++){
    float* cp = C + (rowBase + r0 + i)*128 + c0;
    float4 o0, o1;
    o0.x = acc[i][0]; o0.y = acc[i][1]; o0.z = acc[i][2]; o0.w = acc[i][3];
    o1.x = acc[i][4]; o1.y = acc[i][5]; o1.z = acc[i][6]; o1.w = acc[i][7];
    if (bias){
      o0.x += bias[c0+0]; o0.y += bias[c0+1]; o0.z += bias[c0+2]; o0.w += bias[c0+3];
      o1.x += bias[c0+4]; o1.y += bias[c0+5]; o1.z += bias[c0+6]; o1.w += bias[c0+7];
    }
    *(float4*)cp = o0;
    *(float4*)(cp+4) = o1;
  }
}

// ---------------- GCN aggregation + bias + BN + ReLU (one wave per node) ----------------
__global__ __launch_bounds__(256) void k_agg(const float* __restrict__ m, const int* __restrict__ csr_off,
      const int* __restrict__ csr_src, const float* __restrict__ csr_w, const float* __restrict__ dinv,
      const float* __restrict__ b, const float* __restrict__ gamma, const float* __restrict__ beta,
      const float* __restrict__ mean, const float* __restrict__ var, float* __restrict__ out){
  int gt = blockIdx.x*256 + threadIdx.x;
  int lane = threadIdx.x & 63;
  int n = __builtin_amdgcn_readfirstlane(gt >> 6);
  int c = lane*2;
  float dn = dinv[n];
  float sn = dn*dn;                         // self_norm
  float2 a = *(const float2*)(m + (long)n*H + c);
  float ax = a.x*sn, ay = a.y*sn;
  int e0 = csr_off[n], e1 = csr_off[n+1];
  for (int e = e0; e < e1; e++){
    int s = csr_src[e];
    float wgt = csr_w[e];
    float2 ms = *(const float2*)(m + (long)s*H + c);
    ax = fmaf(ms.x, wgt, ax);
    ay = fmaf(ms.y, wgt, ay);
  }
  float2 r;
  {
    float sc = gamma[c] * rsqrtf(var[c] + EPS);
    float y  = sc*(ax + b[c] - mean[c]) + beta[c];
    r.x = fmaxf(y, 0.0f);
  }
  {
    int c1 = c+1;
    float sc = gamma[c1] * rsqrtf(var[c1] + EPS);
    float y  = sc*(ay + b[c1] - mean[c1]) + beta[c1];
    r.y = fmaxf(y, 0.0f);
  }
  *(float2*)(out + (long)n*H + c) = r;
}

// ---------------- fused cross-attention (shared K/V), in-place on q ----------------
__global__ __launch_bounds__(256) void k_attn(float* __restrict__ q, const float* __restrict__ Kb,
                                              const float* __restrict__ Vb){
  int gt = blockIdx.x*256 + threadIdx.x;
  int lane = threadIdx.x & 63;
  int w = gt >> 6;
  int head = __builtin_amdgcn_readfirstlane(w & 3);       // wave-uniform -> scalar K/V loads
  int ngrp = __builtin_amdgcn_readfirstlane(w >> 2);
  int node = ngrp*64 + lane;
  float* qp = q + (long)node*H + head*HD;
  float qr[HD], o[HD];
  #pragma unroll
  for (int i=0;i<HD;i+=4){
    float4 t = *(const float4*)(qp + i);
    qr[i]=t.x; qr[i+1]=t.y; qr[i+2]=t.z; qr[i+3]=t.w;
  }
  #pragma unroll
  for (int i=0;i<HD;i++) o[i] = 0.0f;
  float l = 0.0f;
  const float* Kh = Kb + head*HD;
  const float* Vh = Vb + head*HD;
  const float scale = 0.17677669529663687f;               // 1/sqrt(32)
  for (int r=0; r<R_RES; r++){
    const float* kr = Kh + (long)r*H;
    float s0=0.f,s1=0.f,s2=0.f,s3=0.f;
    #pragma unroll
    for (int i=0;i<HD;i+=4){
      s0 = fmaf(qr[i+0], kr[i+0], s0);
      s1 = fmaf(qr[i+1], kr[i+1], s1);
      s2 = fmaf(qr[i+2], kr[i+2], s2);
      s3 = fmaf(qr[i+3], kr[i+3], s3);
    }
    float e = __expf(((s0+s1)+(s2+s3))*scale);            // scores small: no max needed
    l += e;
    const float* vr = Vh + (long)r*H;
    #pragma unroll
    for (int i=0;i<HD;i++) o[i] = fmaf(e, vr[i], o[i]);
  }
  float inv = 1.0f / l;
  #pragma unroll
  for (int i=0;i<HD;i+=4){
    float4 t;
    t.x = o[i]*inv; t.y = o[i+1]*inv; t.z = o[i+2]*inv; t.w = o[i+3]*inv;
    *(float4*)(qp + i) = t;
  }
}

// ---------------- per-graph mean pool + classifier ----------------
__global__ __launch_bounds__(128) void k_pool_cls(const float* __restrict__ o, const float* __restrict__ W1,
      const float* __restrict__ b1, const float* __restrict__ W2, const float* __restrict__ b2,
      float* __restrict__ out){
  __shared__ float pooled[128];
  __shared__ float hid[64];
  int g = blockIdx.x, t = threadIdx.x;
  const float* base = o + (long)g*64*H;
  float s = 0.0f;
  for (int j=0;j<64;j++) s += base[j*H + t];
  pooled[t] = s * (1.0f/64.0f);
  __syncthreads();
  if (t < 64){
    float h = b1[t];
    for (int c=0;c<128;c++) h = fmaf(pooled[c], W1[c*64 + t], h);   // cls_W1 [128,64]
    hid[t] = fmaxf(h, 0.0f);
  }
  __syncthreads();
  if (t < 64){
    float v = hid[t]*W2[t];
    #pragma unroll
    for (int off=32; off>0; off>>=1) v += __shfl_down(v, off);
    if (t == 0) out[g] = v + b2[0];
  }
}

extern "C" void kernel_launch(void* const* d_in, const int* in_sizes, int n_in,
                              void* d_out, int out_size, void* d_ws, size_t ws_size,
                              hipStream_t stream){
  const float* x     = (const float*)d_in[0];
  const int*   ei    = (const int*)d_in[1];
  const float* perres= (const float*)d_in[3];
  const float* W0 = (const float*)d_in[4];  const float* b0 = (const float*)d_in[5];
  const float* W1 = (const float*)d_in[6];  const float* b1 = (const float*)d_in[7];
  const float* W2 = (const float*)d_in[8];  const float* b2 = (const float*)d_in[9];
  const float* bng = (const float*)d_in[10]; const float* bnb = (const float*)d_in[11];
  const float* bnm = (const float*)d_in[12]; const float* bnv = (const float*)d_in[13];
  const float* resW = (const float*)d_in[14]; const float* resb = (const float*)d_in[15];
  const float* inW  = (const float*)d_in[16]; const float* inb  = (const float*)d_in[17];
  const float* outW = (const float*)d_in[18]; const float* outb = (const float*)d_in[19];
  const float* cW1 = (const float*)d_in[20]; const float* cb1 = (const float*)d_in[21];
  const float* cW2 = (const float*)d_in[22]; const float* cb2 = (const float*)d_in[23];
  float* out = (float*)d_out;

  char* ws = (char*)d_ws;
  size_t off = 0;
  auto alloc = [&](size_t bytes) -> char* {
    char* p = ws + off;
    off += (bytes + 255) & ~(size_t)255;
    return p;
  };
  float* dinv    = (float*)alloc((size_t)N_NODES*4);
  int*   cnt     = (int*)  alloc((size_t)N_NODES*4);
  int*   cursor  = (int*)  alloc((size_t)N_NODES*4);
  int*   csr_off = (int*)  alloc((size_t)(N_NODES+1)*4);
  int*   csr_src = (int*)  alloc((size_t)N_EDGES*4);
  float* csr_w   = (float*)alloc((size_t)N_EDGES*4);
  float* mbuf    = (float*)alloc((size_t)N_NODES*H*4);
  float* hbuf    = (float*)alloc((size_t)N_NODES*H*4);
  float* resbuf  = (float*)alloc((size_t)R_RES*H*4);
  float* Kbuf    = (float*)alloc((size_t)R_RES*H*4);
  float* Vbuf    = (float*)alloc((size_t)R_RES*H*4);
  if (off > ws_size) return;   // workspace too small -> fail visibly rather than corrupt

  const int* srcI = ei;
  const int* dstI = ei + N_EDGES;

  // CSR build
  hipMemsetAsync(cnt, 0, (size_t)N_NODES*4, stream);
  k_count<<<N_EDGES/256, 256, 0, stream>>>(dstI, cnt, N_EDGES);
  k_scan<<<1, 1024, 0, stream>>>(cnt, csr_off, cursor, dinv);
  k_fill<<<N_EDGES/256, 256, 0, stream>>>(srcI, dstI, dinv, cursor, csr_src, csr_w, N_EDGES);

  const int NB = N_NODES/128;
  // 3 GCN layers: GEMM then gather-aggregate + bias + BN + ReLU
  k_gemm<<<NB, 256, 0, stream>>>(x, W0, nullptr, mbuf, D_IN, 0);
  k_agg<<<N_NODES/4, 256, 0, stream>>>(mbuf, csr_off, csr_src, csr_w, dinv, b0, bng,     bnb,     bnm,     bnv,     hbuf);
  k_gemm<<<NB, 256, 0, stream>>>(hbuf, W1, nullptr, mbuf, H, 0);
  k_agg<<<N_NODES/4, 256, 0, stream>>>(mbuf, csr_off, csr_src, csr_w, dinv, b1, bng+128, bnb+128, bnm+128, bnv+128, hbuf);
  k_gemm<<<NB, 256, 0, stream>>>(hbuf, W2, nullptr, mbuf, H, 0);
  k_agg<<<N_NODES/4, 256, 0, stream>>>(mbuf, csr_off, csr_src, csr_w, dinv, b2, bng+256, bnb+256, bnm+256, bnv+256, hbuf);

  // residue K/V (shared across all nodes)
  k_gemm<<<R_RES/128, 256, 0, stream>>>(perres, resW, resb, resbuf, 25, 0);
  k_gemm<<<R_RES/128, 256, 0, stream>>>(resbuf, inW + 128*128, inb + 128, Kbuf, H, 1);
  k_gemm<<<R_RES/128, 256, 0, stream>>>(resbuf, inW + 256*128, inb + 256, Vbuf, H, 1);

  // q projection, fused attention (in-place on q), out-proj
  k_gemm<<<NB, 256, 0, stream>>>(hbuf, inW, inb, mbuf, H, 1);
  k_attn<<<(N_NODES*NH)/256, 256, 0, stream>>>(mbuf, Kbuf, Vbuf);
  k_gemm<<<NB, 256, 0, stream>>>(mbuf, outW, outb, hbuf, H, 1);

  // pool (64 nodes per graph, batch sorted) + classifier
  k_pool_cls<<<N_GRAPHS, 128, 0, stream>>>(hbuf, cW1, cb1, cW2, cb2, out);
}

// Round 3
// 583.000 us; speedup vs baseline: 1.5439x; 1.5439x over previous
//
#include <hip/hip_runtime.h>
#include <math.h>

#define N_NODES 65536
#define N_EDGES 524288
#define N_GRAPHS 1024
#define H 128
#define R_RES 512
#define NH 4
#define HD 32
#define D_IN 7
#define EPS 1e-5f

typedef __attribute__((ext_vector_type(8))) short short8;
typedef __attribute__((ext_vector_type(4))) float f32x4;
typedef __attribute__((ext_vector_type(4))) unsigned short us4;

__device__ __forceinline__ unsigned short f2bf(float f){
  unsigned u = __builtin_bit_cast(unsigned, f);
  unsigned r = (u + 0x7FFFu + ((u >> 16) & 1u)) >> 16;   // RNE
  return (unsigned short)r;
}
__device__ __forceinline__ float bflo(unsigned u){ return __builtin_bit_cast(float, u << 16); }
__device__ __forceinline__ float bfhi(unsigned u){ return __builtin_bit_cast(float, u & 0xFFFF0000u); }

// ---------------- CSR build ----------------
__global__ __launch_bounds__(256) void k_count(const int* __restrict__ dst, int* __restrict__ cnt, int E){
  int e = blockIdx.x*256 + threadIdx.x;
  if (e < E) atomicAdd(&cnt[dst[e]], 1);
}

__global__ __launch_bounds__(1024) void k_scan(const int* __restrict__ cnt, int* __restrict__ csr_off,
                                               int* __restrict__ cursor, float* __restrict__ dinv){
  __shared__ int part[1024];
  int t = threadIdx.x;
  int base = t*64;
  int s = 0;
  for (int j=0;j<64;j++) s += cnt[base+j];
  part[t] = s;
  __syncthreads();
  for (int off=1; off<1024; off<<=1){
    int v = (t >= off) ? part[t-off] : 0;
    __syncthreads();
    part[t] += v;
    __syncthreads();
  }
  int run = (t == 0) ? 0 : part[t-1];
  for (int j=0;j<64;j++){
    int i = base+j;
    int c = cnt[i];
    csr_off[i] = run;
    cursor[i] = run;
    dinv[i] = rsqrtf(1.0f + (float)c);
    run += c;
  }
  if (t == 0) csr_off[N_NODES] = N_EDGES;
}

__global__ __launch_bounds__(256) void k_fill(const int* __restrict__ src, const int* __restrict__ dst,
      const float* __restrict__ dinv, int* __restrict__ cursor,
      int* __restrict__ csr_src, float* __restrict__ csr_w, int E){
  int e = blockIdx.x*256 + threadIdx.x;
  if (e >= E) return;
  int s = src[e], d = dst[e];
  int p = atomicAdd(&cursor[d], 1);
  csr_src[p] = s;
  csr_w[p] = dinv[s]*dinv[d];
}

// ---------------- layer-0: m = x @ W0, K=7, store bf16 (one wave per node) ----------------
__global__ __launch_bounds__(256) void k_lin0(const float* __restrict__ x, const float* __restrict__ W0,
                                              unsigned short* __restrict__ out){
  int gid = blockIdx.x*256 + threadIdx.x;
  int l = threadIdx.x & 63;
  int n = __builtin_amdgcn_readfirstlane(gid >> 6);
  float a0 = 0.0f, a1 = 0.0f;
  #pragma unroll
  for (int k=0;k<D_IN;k++){
    float xv = x[(long)n*D_IN + k];          // wave-uniform -> scalar load
    float2 wv = *(const float2*)(W0 + k*H + 2*l);
    a0 = fmaf(xv, wv.x, a0); a1 = fmaf(xv, wv.y, a1);
  }
  unsigned pk = (unsigned)f2bf(a0) | ((unsigned)f2bf(a1) << 16);
  *(unsigned*)(out + (long)n*H + 2*l) = pk;
}

// ---------------- bf16 MFMA GEMM: C[M,128] = A_bf16[M,128] @ B (+bias) ----------------
// transB==0: B fp32 [128,128] row-major. transB==1: B(k,c) = Bsrc[c*128+k].
__global__ __launch_bounds__(256) void k_gemm_mfma(const unsigned short* __restrict__ A,
      const float* __restrict__ Bsrc, const float* __restrict__ bias, void* __restrict__ Cout,
      int transB, int outFp32){
  __shared__ unsigned short Bt[128][136];   // Bt[c][k], k-contiguous; stride 272B (16-mult, 2-way banks)
  int tid = threadIdx.x;
  long rowBase = (long)blockIdx.x * 128;
  int w = tid >> 6, l = tid & 63;
  int lc = l & 15, q4 = l >> 4;

  if (transB){
    for (int i = tid; i < 4096; i += 256){
      int c = i >> 5, seg = i & 31;
      float4 v = *(const float4*)(Bsrc + (long)c*128 + seg*4);
      us4 p = {f2bf(v.x), f2bf(v.y), f2bf(v.z), f2bf(v.w)};
      *(us4*)&Bt[c][seg*4] = p;
    }
  } else {
    for (int i = tid; i < 4096; i += 256){
      int k = i >> 5, seg = i & 31;
      float4 v = *(const float4*)(Bsrc + (long)k*128 + seg*4);
      Bt[seg*4+0][k] = f2bf(v.x); Bt[seg*4+1][k] = f2bf(v.y);
      Bt[seg*4+2][k] = f2bf(v.z); Bt[seg*4+3][k] = f2bf(v.w);
    }
  }

  // prefetch A fragments (wave reads 16 rows x 64B contiguous per chunk)
  short8 af[2][4];
  #pragma unroll
  for (int rt=0;rt<2;rt++){
    long row = rowBase + w*32 + rt*16 + lc;
    #pragma unroll
    for (int kc=0;kc<4;kc++)
      af[rt][kc] = *(const short8*)(A + row*128 + kc*32 + q4*8);
  }

  f32x4 acc[2][8];
  #pragma unroll
  for (int rt=0;rt<2;rt++)
    #pragma unroll
    for (int ct=0;ct<8;ct++) acc[rt][ct] = (f32x4){0.f,0.f,0.f,0.f};

  __syncthreads();

  #pragma unroll
  for (int kc=0;kc<4;kc++){
    #pragma unroll
    for (int ct=0;ct<8;ct++){
      short8 bf = *(const short8*)&Bt[ct*16 + lc][kc*32 + q4*8];
      acc[0][ct] = __builtin_amdgcn_mfma_f32_16x16x32_bf16(af[0][kc], bf, acc[0][ct], 0,0,0);
      acc[1][ct] = __builtin_amdgcn_mfma_f32_16x16x32_bf16(af[1][kc], bf, acc[1][ct], 0,0,0);
    }
  }

  float bv[8];
  #pragma unroll
  for (int ct=0;ct<8;ct++) bv[ct] = bias ? bias[ct*16 + lc] : 0.0f;
  #pragma unroll
  for (int rt=0;rt<2;rt++){
    #pragma unroll
    for (int ct=0;ct<8;ct++){
      #pragma unroll
      for (int i=0;i<4;i++){
        long row = rowBase + w*32 + rt*16 + q4*4 + i;   // C layout: col=lane&15, row=quad*4+reg
        int col = ct*16 + lc;
        float v = acc[rt][ct][i] + bv[ct];
        if (outFp32) ((float*)Cout)[row*128 + col] = v;
        else ((unsigned short*)Cout)[row*128 + col] = f2bf(v);
      }
    }
  }
}

// ---------------- GCN aggregation + bias + BN + ReLU, bf16 in/out ----------------
__global__ __launch_bounds__(256) void k_agg(const unsigned short* __restrict__ m, const int* __restrict__ csr_off,
      const int* __restrict__ csr_src, const float* __restrict__ csr_w, const float* __restrict__ dinv,
      const float* __restrict__ b, const float* __restrict__ gamma, const float* __restrict__ beta,
      const float* __restrict__ mean, const float* __restrict__ var, unsigned short* __restrict__ out){
  int gt = blockIdx.x*256 + threadIdx.x;
  int lane = threadIdx.x & 63;
  int n = __builtin_amdgcn_readfirstlane(gt >> 6);
  int c = lane*2;
  float dn = dinv[n];
  float sn = dn*dn;
  unsigned ua = *(const unsigned*)(m + (long)n*H + c);
  float ax = bflo(ua)*sn, ay = bfhi(ua)*sn;
  int e0 = csr_off[n], e1 = csr_off[n+1];
  for (int e = e0; e < e1; e++){
    int s = csr_src[e];
    float wgt = csr_w[e];
    unsigned us = *(const unsigned*)(m + (long)s*H + c);
    ax = fmaf(bflo(us), wgt, ax);
    ay = fmaf(bfhi(us), wgt, ay);
  }
  float rx, ry;
  {
    float sc = gamma[c] * rsqrtf(var[c] + EPS);
    rx = fmaxf(sc*(ax + b[c] - mean[c]) + beta[c], 0.0f);
  }
  {
    int c1 = c+1;
    float sc = gamma[c1] * rsqrtf(var[c1] + EPS);
    ry = fmaxf(sc*(ay + b[c1] - mean[c1]) + beta[c1], 0.0f);
  }
  unsigned pk = (unsigned)f2bf(rx) | ((unsigned)f2bf(ry) << 16);
  *(unsigned*)(out + (long)n*H + c) = pk;
}

// ---------------- fp32 GEMM (kept for small 512-row projections) ----------------
__global__ __launch_bounds__(256,2) void k_gemm(const float* __restrict__ A, const float* __restrict__ B,
      const float* __restrict__ bias, float* __restrict__ C, int K, int transB){
  __shared__ float Bs[128][132];
  __shared__ float As[16][128];
  int tid = threadIdx.x;
  long rowBase = (long)blockIdx.x * 128;

  if (!transB){
    for (int idx = tid; idx < 128*128; idx += 256){
      int k = idx >> 7, c = idx & 127;
      Bs[k][c] = (k < K) ? B[(long)k*128 + c] : 0.0f;
    }
  } else {
    for (int idx = tid; idx < 128*128; idx += 256){
      int c = idx >> 7, k = idx & 127;
      Bs[k][c] = (k < K) ? B[(long)c*K + k] : 0.0f;
    }
  }

  float acc[8][8];
  #pragma unroll
  for (int i=0;i<8;i++)
    #pragma unroll
    for (int j=0;j<8;j++) acc[i][j] = 0.0f;

  int rg = tid >> 4, cg = tid & 15;
  int r0 = rg*8, c0 = cg*8;
  int srow = tid >> 1, skoff = (tid & 1)*8;
  const bool fast = ((K & 15) == 0);

  for (int k0 = 0; k0 < K; k0 += 16){
    __syncthreads();
    const float* ap = A + (rowBase + srow)*K + k0 + skoff;
    if (fast){
      float4 v0 = *(const float4*)(ap);
      float4 v1 = *(const float4*)(ap + 4);
      As[skoff+0][srow] = v0.x; As[skoff+1][srow] = v0.y;
      As[skoff+2][srow] = v0.z; As[skoff+3][srow] = v0.w;
      As[skoff+4][srow] = v1.x; As[skoff+5][srow] = v1.y;
      As[skoff+6][srow] = v1.z; As[skoff+7][srow] = v1.w;
    } else {
      #pragma unroll
      for (int j=0;j<8;j++){
        int kk = k0 + skoff + j;
        As[skoff+j][srow] = (kk < K) ? ap[j] : 0.0f;
      }
    }
    __syncthreads();
    #pragma unroll
    for (int k=0;k<16;k++){
      float4 a0 = *(const float4*)(&As[k][r0]);
      float4 a1 = *(const float4*)(&As[k][r0+4]);
      float4 b0 = *(const float4*)(&Bs[k0+k][c0]);
      float4 b1 = *(const float4*)(&Bs[k0+k][c0+4]);
      float a[8] = {a0.x,a0.y,a0.z,a0.w,a1.x,a1.y,a1.z,a1.w};
      float b[8] = {b0.x,b0.y,b0.z,b0.w,b1.x,b1.y,b1.z,b1.w};
      #pragma unroll
      for (int i=0;i<8;i++)
        #pragma unroll
        for (int j=0;j<8;j++)
          acc[i][j] = fmaf(a[i], b[j], acc[i][j]);
    }
  }

  #pragma unroll
  for (int i=0;i<8;i++){
    float* cp = C + (rowBase + r0 + i)*128 + c0;
    float4 o0, o1;
    o0.x = acc[i][0]; o0.y = acc[i][1]; o0.z = acc[i][2]; o0.w = acc[i][3];
    o1.x = acc[i][4]; o1.y = acc[i][5]; o1.z = acc[i][6]; o1.w = acc[i][7];
    if (bias){
      o0.x += bias[c0+0]; o0.y += bias[c0+1]; o0.z += bias[c0+2]; o0.w += bias[c0+3];
      o1.x += bias[c0+4]; o1.y += bias[c0+5]; o1.z += bias[c0+6]; o1.w += bias[c0+7];
    }
    *(float4*)cp = o0;
    *(float4*)(cp+4) = o1;
  }
}

// ---------------- MFMA flash cross-attention: block = 256 nodes x 1 head ----------------
__global__ __launch_bounds__(256) void k_attn(unsigned short* __restrict__ q,
      const float* __restrict__ Kb, const float* __restrict__ Vb){
  __shared__ unsigned short Kl[R_RES][40];     // K[res][dim], stride 80B (16-mult, 2-way banks)
  __shared__ unsigned short Vt[HD][520];       // V^T[dim][res], stride 1040B (16-mult, 2-way banks)
  __shared__ unsigned short Pl[4][16][40];     // per-wave P[node][res32], stride 80B
  int tid = threadIdx.x;
  int h = blockIdx.y;
  long nbase = (long)blockIdx.x * 256;

  // stage K and V^T (bf16) for this head
  for (int i = tid; i < R_RES*8; i += 256){
    int r = i >> 3, seg = i & 7;
    float4 v = *(const float4*)(Kb + (long)r*H + h*HD + seg*4);
    us4 p = {f2bf(v.x), f2bf(v.y), f2bf(v.z), f2bf(v.w)};
    *(us4*)&Kl[r][seg*4] = p;
  }
  for (int i = tid; i < R_RES*8; i += 256){
    int r = i >> 3, seg = i & 7;
    float4 v = *(const float4*)(Vb + (long)r*H + h*HD + seg*4);
    Vt[seg*4+0][r] = f2bf(v.x); Vt[seg*4+1][r] = f2bf(v.y);
    Vt[seg*4+2][r] = f2bf(v.z); Vt[seg*4+3][r] = f2bf(v.w);
  }
  __syncthreads();

  int w = tid >> 6, l = tid & 63;
  int lc = l & 15, q4 = l >> 4;
  const float scale = 0.17677669529663687f;    // 1/sqrt(32)

  for (int nt = 0; nt < 4; nt++){
    long tbase = nbase + w*64 + nt*16;
    short8 qf = *(const short8*)(q + (tbase + lc)*H + h*HD + q4*8);   // A-frag: m=lane&15, k=quad*8+j
    f32x4 o0 = {0.f,0.f,0.f,0.f}, o1 = {0.f,0.f,0.f,0.f};
    float ls0=0.f, ls1=0.f, ls2=0.f, ls3=0.f;

    for (int ch = 0; ch < 16; ch++){
      #pragma unroll
      for (int half = 0; half < 2; half++){
        int rt = ch*2 + half;
        short8 kf = *(const short8*)&Kl[rt*16 + lc][q4*8];
        f32x4 s = {0.f,0.f,0.f,0.f};
        s = __builtin_amdgcn_mfma_f32_16x16x32_bf16(qf, kf, s, 0,0,0);
        float e0 = __expf(s[0]*scale);
        float e1 = __expf(s[1]*scale);
        float e2 = __expf(s[2]*scale);
        float e3 = __expf(s[3]*scale);
        ls0 += e0; ls1 += e1; ls2 += e2; ls3 += e3;
        int col = half*16 + lc;
        Pl[w][q4*4+0][col] = f2bf(e0);
        Pl[w][q4*4+1][col] = f2bf(e1);
        Pl[w][q4*4+2][col] = f2bf(e2);
        Pl[w][q4*4+3][col] = f2bf(e3);
      }
      short8 pf = *(const short8*)&Pl[w][lc][q4*8];          // A-frag of P
      short8 v0 = *(const short8*)&Vt[lc][ch*32 + q4*8];     // B-frag: k=res, n=dim 0..15
      short8 v1 = *(const short8*)&Vt[16 + lc][ch*32 + q4*8];// dims 16..31
      o0 = __builtin_amdgcn_mfma_f32_16x16x32_bf16(pf, v0, o0, 0,0,0);
      o1 = __builtin_amdgcn_mfma_f32_16x16x32_bf16(pf, v1, o1, 0,0,0);
    }

    // row sums: reduce over the 16 column-lanes within each quad
    #pragma unroll
    for (int msk = 1; msk < 16; msk <<= 1){
      ls0 += __shfl_xor(ls0, msk); ls1 += __shfl_xor(ls1, msk);
      ls2 += __shfl_xor(ls2, msk); ls3 += __shfl_xor(ls3, msk);
    }
    float inv[4] = {1.0f/ls0, 1.0f/ls1, 1.0f/ls2, 1.0f/ls3};
    #pragma unroll
    for (int i=0;i<4;i++){
      long node = tbase + q4*4 + i;        // C layout: row=quad*4+reg, col=lane&15
      q[node*H + h*HD + lc]      = f2bf(o0[i]*inv[i]);
      q[node*H + h*HD + 16 + lc] = f2bf(o1[i]*inv[i]);
    }
  }
}

// ---------------- per-graph mean pool + classifier (fp32) ----------------
__global__ __launch_bounds__(128) void k_pool_cls(const float* __restrict__ o, const float* __restrict__ W1,
      const float* __restrict__ b1, const float* __restrict__ W2, const float* __restrict__ b2,
      float* __restrict__ out){
  __shared__ float pooled[128];
  __shared__ float hid[64];
  int g = blockIdx.x, t = threadIdx.x;
  const float* base = o + (long)g*64*H;
  float s = 0.0f;
  for (int j=0;j<64;j++) s += base[j*H + t];
  pooled[t] = s * (1.0f/64.0f);
  __syncthreads();
  if (t < 64){
    float hh = b1[t];
    for (int c=0;c<128;c++) hh = fmaf(pooled[c], W1[c*64 + t], hh);
    hid[t] = fmaxf(hh, 0.0f);
  }
  __syncthreads();
  if (t < 64){
    float v = hid[t]*W2[t];
    #pragma unroll
    for (int off=32; off>0; off>>=1) v += __shfl_down(v, off);
    if (t == 0) out[g] = v + b2[0];
  }
}

extern "C" void kernel_launch(void* const* d_in, const int* in_sizes, int n_in,
                              void* d_out, int out_size, void* d_ws, size_t ws_size,
                              hipStream_t stream){
  const float* x     = (const float*)d_in[0];
  const int*   ei    = (const int*)d_in[1];
  const float* perres= (const float*)d_in[3];
  const float* W0 = (const float*)d_in[4];
  const float* b0 = (const float*)d_in[5];
  const float* W1 = (const float*)d_in[6];  const float* b1 = (const float*)d_in[7];
  const float* W2 = (const float*)d_in[8];  const float* b2 = (const float*)d_in[9];
  const float* bng = (const float*)d_in[10]; const float* bnb = (const float*)d_in[11];
  const float* bnm = (const float*)d_in[12]; const float* bnv = (const float*)d_in[13];
  const float* resW = (const float*)d_in[14]; const float* resb = (const float*)d_in[15];
  const float* inW  = (const float*)d_in[16]; const float* inb  = (const float*)d_in[17];
  const float* outW = (const float*)d_in[18]; const float* outb = (const float*)d_in[19];
  const float* cW1 = (const float*)d_in[20]; const float* cb1 = (const float*)d_in[21];
  const float* cW2 = (const float*)d_in[22]; const float* cb2 = (const float*)d_in[23];
  float* out = (float*)d_out;

  char* ws = (char*)d_ws;
  size_t off = 0;
  auto alloc = [&](size_t bytes) -> char* {
    char* p = ws + off;
    off += (bytes + 255) & ~(size_t)255;
    return p;
  };
  float* dinv    = (float*)alloc((size_t)N_NODES*4);
  int*   cnt     = (int*)  alloc((size_t)N_NODES*4);
  int*   cursor  = (int*)  alloc((size_t)N_NODES*4);
  int*   csr_off = (int*)  alloc((size_t)(N_NODES+1)*4);
  int*   csr_src = (int*)  alloc((size_t)N_EDGES*4);
  float* csr_w   = (float*)alloc((size_t)N_EDGES*4);
  unsigned short* mb  = (unsigned short*)alloc((size_t)N_NODES*H*2);  // bf16: m / q / o
  unsigned short* hb  = (unsigned short*)alloc((size_t)N_NODES*H*2);  // bf16: h
  float* hf32    = (float*)alloc((size_t)N_NODES*H*4);                // fp32: out-proj result
  float* resbuf  = (float*)alloc((size_t)R_RES*H*4);
  float* Kbuf    = (float*)alloc((size_t)R_RES*H*4);
  float* Vbuf    = (float*)alloc((size_t)R_RES*H*4);
  if (off > ws_size) return;

  const int* srcI = ei;
  const int* dstI = ei + N_EDGES;

  // CSR build
  hipMemsetAsync(cnt, 0, (size_t)N_NODES*4, stream);
  k_count<<<N_EDGES/256, 256, 0, stream>>>(dstI, cnt, N_EDGES);
  k_scan<<<1, 1024, 0, stream>>>(cnt, csr_off, cursor, dinv);
  k_fill<<<N_EDGES/256, 256, 0, stream>>>(srcI, dstI, dinv, cursor, csr_src, csr_w, N_EDGES);

  const int NB = N_NODES/128;
  // GCN layer 0 (K=7 on VALU), then MFMA GEMMs for layers 1/2
  k_lin0<<<N_NODES/4, 256, 0, stream>>>(x, W0, mb);
  k_agg<<<N_NODES/4, 256, 0, stream>>>(mb, csr_off, csr_src, csr_w, dinv, b0, bng,     bnb,     bnm,     bnv,     hb);
  k_gemm_mfma<<<NB, 256, 0, stream>>>(hb, W1, nullptr, mb, 0, 0);
  k_agg<<<N_NODES/4, 256, 0, stream>>>(mb, csr_off, csr_src, csr_w, dinv, b1, bng+128, bnb+128, bnm+128, bnv+128, hb);
  k_gemm_mfma<<<NB, 256, 0, stream>>>(hb, W2, nullptr, mb, 0, 0);
  k_agg<<<N_NODES/4, 256, 0, stream>>>(mb, csr_off, csr_src, csr_w, dinv, b2, bng+256, bnb+256, bnm+256, bnv+256, hb);

  // residue K/V (fp32 precision until attention staging)
  k_gemm<<<R_RES/128, 256, 0, stream>>>(perres, resW, resb, resbuf, 25, 0);
  k_gemm<<<R_RES/128, 256, 0, stream>>>(resbuf, inW + 128*128, inb + 128, Kbuf, H, 1);
  k_gemm<<<R_RES/128, 256, 0, stream>>>(resbuf, inW + 256*128, inb + 256, Vbuf, H, 1);

  // q projection (bf16), fused MFMA attention (in-place on q), out-proj (fp32 out)
  k_gemm_mfma<<<NB, 256, 0, stream>>>(hb, inW, inb, mb, 1, 0);
  dim3 agrid(N_NODES/256, NH);
  k_attn<<<agrid, 256, 0, stream>>>(mb, Kbuf, Vbuf);
  k_gemm_mfma<<<NB, 256, 0, stream>>>(mb, outW, outb, hf32, 1, 1);

  // pool + classifier
  k_pool_cls<<<N_GRAPHS, 128, 0, stream>>>(hf32, cW1, cb1, cW2, cb2, out);
}

// Round 4
// 482.370 us; speedup vs baseline: 1.8660x; 1.2086x over previous
//
#include <hip/hip_runtime.h>
#include <math.h>

#define N_NODES 65536
#define N_EDGES 524288
#define N_GRAPHS 1024
#define H 128
#define R_RES 512
#define NH 4
#define HD 32
#define D_IN 7
#define EPS 1e-5f

typedef __attribute__((ext_vector_type(8))) short short8;
typedef __attribute__((ext_vector_type(4))) float f32x4;
typedef __attribute__((ext_vector_type(4))) unsigned uint4v;

#if __has_builtin(__builtin_amdgcn_exp2f)
#define EXP2F __builtin_amdgcn_exp2f
#else
#define EXP2F exp2f
#endif
#if __has_builtin(__builtin_amdgcn_rcpf)
#define RCPF __builtin_amdgcn_rcpf
#else
#define RCPF(x) (1.0f/(x))
#endif

// round-half-up bf16 (1 add vs 4-op RNE; max 0.5ulp, bias-free in practice)
__device__ __forceinline__ unsigned short rnd_bf16(float f){
  return (unsigned short)((__builtin_bit_cast(unsigned, f) + 0x8000u) >> 16);
}
// pack two floats -> bf16x2 in one v_perm (lo in low half)
__device__ __forceinline__ unsigned pk_bf16(float lo, float hi){
  unsigned a = __builtin_bit_cast(unsigned, lo) + 0x8000u;
  unsigned b = __builtin_bit_cast(unsigned, hi) + 0x8000u;
  return __builtin_amdgcn_perm(b, a, 0x07060302u);   // {b.hi16, a.hi16}
}
__device__ __forceinline__ float bflo(unsigned u){ return __builtin_bit_cast(float, u << 16); }
__device__ __forceinline__ float bfhi(unsigned u){ return __builtin_bit_cast(float, u & 0xFFFF0000u); }

// ---------------- CSR build ----------------
__global__ __launch_bounds__(256) void k_count(const int* __restrict__ dst, int* __restrict__ cnt, int E){
  int e = blockIdx.x*256 + threadIdx.x;
  if (e < E) atomicAdd(&cnt[dst[e]], 1);
}

__global__ __launch_bounds__(1024) void k_scan(const int* __restrict__ cnt, int* __restrict__ csr_off,
                                               int* __restrict__ cursor, float* __restrict__ dinv){
  __shared__ int part[1024];
  int t = threadIdx.x;
  int base = t*64;
  int s = 0;
  for (int j=0;j<64;j++) s += cnt[base+j];
  part[t] = s;
  __syncthreads();
  for (int off=1; off<1024; off<<=1){
    int v = (t >= off) ? part[t-off] : 0;
    __syncthreads();
    part[t] += v;
    __syncthreads();
  }
  int run = (t == 0) ? 0 : part[t-1];
  for (int j=0;j<64;j++){
    int i = base+j;
    int c = cnt[i];
    csr_off[i] = run;
    cursor[i] = run;
    dinv[i] = rsqrtf(1.0f + (float)c);
    run += c;
  }
  if (t == 0) csr_off[N_NODES] = N_EDGES;
}

__global__ __launch_bounds__(256) void k_fill(const int* __restrict__ src, const int* __restrict__ dst,
      const float* __restrict__ dinv, int* __restrict__ cursor,
      int* __restrict__ csr_src, float* __restrict__ csr_w, int E){
  int e = blockIdx.x*256 + threadIdx.x;
  if (e >= E) return;
  int s = src[e], d = dst[e];
  int p = atomicAdd(&cursor[d], 1);
  csr_src[p] = s;
  csr_w[p] = dinv[s]*dinv[d];
}

// ---------------- layer-0: m = x @ W0, K=7, bf16 out ----------------
__global__ __launch_bounds__(256) void k_lin0(const float* __restrict__ x, const float* __restrict__ W0,
                                              unsigned short* __restrict__ out){
  int gid = blockIdx.x*256 + threadIdx.x;
  int l = threadIdx.x & 63;
  int n = __builtin_amdgcn_readfirstlane(gid >> 6);
  float a0 = 0.0f, a1 = 0.0f;
  #pragma unroll
  for (int k=0;k<D_IN;k++){
    float xv = x[(long)n*D_IN + k];
    float2 wv = *(const float2*)(W0 + k*H + 2*l);
    a0 = fmaf(xv, wv.x, a0); a1 = fmaf(xv, wv.y, a1);
  }
  *(unsigned*)(out + (long)n*H + 2*l) = pk_bf16(a0, a1);
}

// ---------------- bf16 MFMA GEMM: C[M,128] = A_bf16[M,128] @ B, out=(acc+bias)*scale ----------------
__global__ __launch_bounds__(256) void k_gemm_mfma(const unsigned short* __restrict__ A,
      const float* __restrict__ Bsrc, const float* __restrict__ bias, void* __restrict__ Cout,
      int transB, int outFp32, float scale){
  __shared__ unsigned short Bt[128][136];   // Bt[c][k], k-contiguous
  int tid = threadIdx.x;
  long rowBase = (long)blockIdx.x * 128;
  int w = tid >> 6, l = tid & 63;
  int lc = l & 15, q4 = l >> 4;

  if (transB){
    for (int i = tid; i < 4096; i += 256){
      int c = i >> 5, seg = i & 31;
      float4 v = *(const float4*)(Bsrc + (long)c*128 + seg*4);
      uint2 p; p.x = pk_bf16(v.x, v.y); p.y = pk_bf16(v.z, v.w);
      *(uint2*)&Bt[c][seg*4] = p;
    }
  } else {
    for (int i = tid; i < 4096; i += 256){
      int k = i >> 5, seg = i & 31;
      float4 v = *(const float4*)(Bsrc + (long)k*128 + seg*4);
      Bt[seg*4+0][k] = rnd_bf16(v.x); Bt[seg*4+1][k] = rnd_bf16(v.y);
      Bt[seg*4+2][k] = rnd_bf16(v.z); Bt[seg*4+3][k] = rnd_bf16(v.w);
    }
  }

  short8 af[2][4];
  #pragma unroll
  for (int rt=0;rt<2;rt++){
    long row = rowBase + w*32 + rt*16 + lc;
    #pragma unroll
    for (int kc=0;kc<4;kc++)
      af[rt][kc] = *(const short8*)(A + row*128 + kc*32 + q4*8);
  }

  f32x4 acc[2][8];
  #pragma unroll
  for (int rt=0;rt<2;rt++)
    #pragma unroll
    for (int ct=0;ct<8;ct++) acc[rt][ct] = (f32x4){0.f,0.f,0.f,0.f};

  __syncthreads();

  #pragma unroll
  for (int kc=0;kc<4;kc++){
    #pragma unroll
    for (int ct=0;ct<8;ct++){
      short8 bf = *(const short8*)&Bt[ct*16 + lc][kc*32 + q4*8];
      acc[0][ct] = __builtin_amdgcn_mfma_f32_16x16x32_bf16(af[0][kc], bf, acc[0][ct], 0,0,0);
      acc[1][ct] = __builtin_amdgcn_mfma_f32_16x16x32_bf16(af[1][kc], bf, acc[1][ct], 0,0,0);
    }
  }

  float bv[8];
  #pragma unroll
  for (int ct=0;ct<8;ct++) bv[ct] = bias ? bias[ct*16 + lc] : 0.0f;
  #pragma unroll
  for (int rt=0;rt<2;rt++){
    #pragma unroll
    for (int ct=0;ct<8;ct++){
      #pragma unroll
      for (int i=0;i<4;i++){
        long row = rowBase + w*32 + rt*16 + q4*4 + i;   // C layout: col=lane&15, row=quad*4+reg
        int col = ct*16 + lc;
        float v = (acc[rt][ct][i] + bv[ct]) * scale;
        if (outFp32) ((float*)Cout)[row*128 + col] = v;
        else ((unsigned short*)Cout)[row*128 + col] = rnd_bf16(v);
      }
    }
  }
}

// ---------------- GCN aggregation + bias + BN + ReLU, bf16 in/out ----------------
__global__ __launch_bounds__(256) void k_agg(const unsigned short* __restrict__ m, const int* __restrict__ csr_off,
      const int* __restrict__ csr_src, const float* __restrict__ csr_w, const float* __restrict__ dinv,
      const float* __restrict__ b, const float* __restrict__ gamma, const float* __restrict__ beta,
      const float* __restrict__ mean, const float* __restrict__ var, unsigned short* __restrict__ out){
  int gt = blockIdx.x*256 + threadIdx.x;
  int lane = threadIdx.x & 63;
  int n = __builtin_amdgcn_readfirstlane(gt >> 6);
  int c = lane*2;
  float dn = dinv[n];
  float sn = dn*dn;
  unsigned ua = *(const unsigned*)(m + (long)n*H + c);
  float ax = bflo(ua)*sn, ay = bfhi(ua)*sn;
  int e0 = csr_off[n], e1 = csr_off[n+1];
  int e = e0;
  for (; e + 2 <= e1; e += 2){           // 2-way unroll: two gathers in flight
    int s0 = csr_src[e],   s1 = csr_src[e+1];
    float w0 = csr_w[e],   w1 = csr_w[e+1];
    unsigned u0 = *(const unsigned*)(m + (long)s0*H + c);
    unsigned u1 = *(const unsigned*)(m + (long)s1*H + c);
    ax = fmaf(bflo(u0), w0, ax); ay = fmaf(bfhi(u0), w0, ay);
    ax = fmaf(bflo(u1), w1, ax); ay = fmaf(bfhi(u1), w1, ay);
  }
  if (e < e1){
    int s0 = csr_src[e]; float w0 = csr_w[e];
    unsigned u0 = *(const unsigned*)(m + (long)s0*H + c);
    ax = fmaf(bflo(u0), w0, ax); ay = fmaf(bfhi(u0), w0, ay);
  }
  float rx, ry;
  {
    float sc = gamma[c] * rsqrtf(var[c] + EPS);
    rx = fmaxf(sc*(ax + b[c] - mean[c]) + beta[c], 0.0f);
  }
  {
    int c1 = c+1;
    float sc = gamma[c1] * rsqrtf(var[c1] + EPS);
    ry = fmaxf(sc*(ay + b[c1] - mean[c1]) + beta[c1], 0.0f);
  }
  *(unsigned*)(out + (long)n*H + c) = pk_bf16(rx, ry);
}

// ---------------- fp32 GEMM (res projection, K=25), bf16 or fp32 out ----------------
__global__ __launch_bounds__(256,2) void k_gemm(const float* __restrict__ A, const float* __restrict__ B,
      const float* __restrict__ bias, void* __restrict__ C, int K, int transB, int outBf16){
  __shared__ float Bs[128][132];
  __shared__ float As[16][128];
  int tid = threadIdx.x;
  long rowBase = (long)blockIdx.x * 128;

  if (!transB){
    for (int idx = tid; idx < 128*128; idx += 256){
      int k = idx >> 7, c = idx & 127;
      Bs[k][c] = (k < K) ? B[(long)k*128 + c] : 0.0f;
    }
  } else {
    for (int idx = tid; idx < 128*128; idx += 256){
      int c = idx >> 7, k = idx & 127;
      Bs[k][c] = (k < K) ? B[(long)c*K + k] : 0.0f;
    }
  }

  float acc[8][8];
  #pragma unroll
  for (int i=0;i<8;i++)
    #pragma unroll
    for (int j=0;j<8;j++) acc[i][j] = 0.0f;

  int rg = tid >> 4, cg = tid & 15;
  int r0 = rg*8, c0 = cg*8;
  int srow = tid >> 1, skoff = (tid & 1)*8;
  const bool fast = ((K & 15) == 0);

  for (int k0 = 0; k0 < K; k0 += 16){
    __syncthreads();
    const float* ap = A + (rowBase + srow)*K + k0 + skoff;
    if (fast){
      float4 v0 = *(const float4*)(ap);
      float4 v1 = *(const float4*)(ap + 4);
      As[skoff+0][srow] = v0.x; As[skoff+1][srow] = v0.y;
      As[skoff+2][srow] = v0.z; As[skoff+3][srow] = v0.w;
      As[skoff+4][srow] = v1.x; As[skoff+5][srow] = v1.y;
      As[skoff+6][srow] = v1.z; As[skoff+7][srow] = v1.w;
    } else {
      #pragma unroll
      for (int j=0;j<8;j++){
        int kk = k0 + skoff + j;
        As[skoff+j][srow] = (kk < K) ? ap[j] : 0.0f;
      }
    }
    __syncthreads();
    #pragma unroll
    for (int k=0;k<16;k++){
      float4 a0 = *(const float4*)(&As[k][r0]);
      float4 a1 = *(const float4*)(&As[k][r0+4]);
      float4 b0 = *(const float4*)(&Bs[k0+k][c0]);
      float4 b1 = *(const float4*)(&Bs[k0+k][c0+4]);
      float a[8] = {a0.x,a0.y,a0.z,a0.w,a1.x,a1.y,a1.z,a1.w};
      float b[8] = {b0.x,b0.y,b0.z,b0.w,b1.x,b1.y,b1.z,b1.w};
      #pragma unroll
      for (int i=0;i<8;i++)
        #pragma unroll
        for (int j=0;j<8;j++)
          acc[i][j] = fmaf(a[i], b[j], acc[i][j]);
    }
  }

  #pragma unroll
  for (int i=0;i<8;i++){
    float o[8];
    #pragma unroll
    for (int j=0;j<8;j++) o[j] = acc[i][j] + (bias ? bias[c0+j] : 0.0f);
    long row = rowBase + r0 + i;
    if (outBf16){
      uint4v p;
      p.x = pk_bf16(o[0],o[1]); p.y = pk_bf16(o[2],o[3]);
      p.z = pk_bf16(o[4],o[5]); p.w = pk_bf16(o[6],o[7]);
      *(uint4v*)((unsigned short*)C + row*128 + c0) = p;
    } else {
      float* cp = (float*)C + row*128 + c0;
      *(float4*)cp = (float4){o[0],o[1],o[2],o[3]};
      *(float4*)(cp+4) = (float4){o[4],o[5],o[6],o[7]};
    }
  }
}

// ---------------- MFMA flash cross-attention: block = 256 nodes x 1 head ----------------
// q holds (h@Wq + bq) * (log2e/sqrt(HD)) in bf16; exp2 gives softmax numerator.
__global__ __launch_bounds__(256) void k_attn(unsigned short* __restrict__ q,
      const float* __restrict__ Kb, const float* __restrict__ Vb){
  __shared__ unsigned short Kl[R_RES][32];   // K[res][dim], stride 64B: balanced min-phase
  __shared__ unsigned short Vt[HD][520];     // V^T[dim][res], stride 1040B: balanced
  __shared__ float Pf[4][16][36];            // per-wave exp(S) f32 [node][res32], stride 144B
  int tid = threadIdx.x;
  int h = blockIdx.y;
  int w = tid >> 6, l = tid & 63;
  int lc = l & 15, q4 = l >> 4;

  // stage K (bf16): thread i -> res r=i>>3, 4 dims
  for (int i = tid; i < R_RES*8; i += 256){
    int r = i >> 3, seg = i & 7;
    float4 v = *(const float4*)(Kb + (long)r*H + h*HD + seg*4);
    uint2 p; p.x = pk_bf16(v.x, v.y); p.y = pk_bf16(v.z, v.w);
    *(uint2*)&Kl[r][seg*4] = p;
  }
  // stage V^T (bf16): thread i -> dim d=i&31, res-quad rq=i>>5 (conflict-free us4 writes)
  for (int i = tid; i < HD*(R_RES/4); i += 256){
    int d = i & 31, rq = i >> 5;
    const float* vp = Vb + (long)(rq*4)*H + h*HD + d;
    float a0 = vp[0], a1 = vp[H], a2 = vp[2*H], a3 = vp[3*H];
    uint2 p; p.x = pk_bf16(a0, a1); p.y = pk_bf16(a2, a3);
    *(uint2*)&Vt[d][rq*4] = p;
  }
  __syncthreads();

  long nb = (long)blockIdx.x*256 + w*64;

  // B-frag of ones-column (for row sums via MFMA): col n=0 all-ones
  short one = (lc == 0) ? (short)0x3F80 : (short)0;
  short8 vones = {one,one,one,one,one,one,one,one};

  short8 qf[4];
  #pragma unroll
  for (int nt=0;nt<4;nt++)
    qf[nt] = *(const short8*)(q + (nb + nt*16 + lc)*H + h*HD + q4*8);

  f32x4 o0[4], o1[4], o2[4];
  #pragma unroll
  for (int nt=0;nt<4;nt++){
    o0[nt] = (f32x4){0.f,0.f,0.f,0.f};
    o1[nt] = (f32x4){0.f,0.f,0.f,0.f};
    o2[nt] = (f32x4){0.f,0.f,0.f,0.f};
  }

  for (int ch = 0; ch < 16; ch++){
    short8 kf0 = *(const short8*)&Kl[ch*32 + lc][q4*8];
    short8 kf1 = *(const short8*)&Kl[ch*32 + 16 + lc][q4*8];
    short8 v0  = *(const short8*)&Vt[lc][ch*32 + q4*8];
    short8 v1  = *(const short8*)&Vt[16 + lc][ch*32 + q4*8];
    #pragma unroll
    for (int nt=0;nt<4;nt++){
      f32x4 z = {0.f,0.f,0.f,0.f};
      f32x4 sa = __builtin_amdgcn_mfma_f32_16x16x32_bf16(qf[nt], kf0, z, 0,0,0);
      f32x4 sb = __builtin_amdgcn_mfma_f32_16x16x32_bf16(qf[nt], kf1, z, 0,0,0);
      #pragma unroll
      for (int i=0;i<4;i++){
        Pf[w][q4*4+i][lc]      = EXP2F(sa[i]);   // 2-way bank: free
        Pf[w][q4*4+i][16 + lc] = EXP2F(sb[i]);
      }
      // wave-private round-trip (in-order DS ops; no barrier needed)
      float4 pa = *(const float4*)&Pf[w][lc][q4*8];
      float4 pb = *(const float4*)&Pf[w][lc][q4*8 + 4];
      uint4v pk;
      pk.x = pk_bf16(pa.x, pa.y); pk.y = pk_bf16(pa.z, pa.w);
      pk.z = pk_bf16(pb.x, pb.y); pk.w = pk_bf16(pb.z, pb.w);
      short8 pf = __builtin_bit_cast(short8, pk);
      o0[nt] = __builtin_amdgcn_mfma_f32_16x16x32_bf16(pf, v0,    o0[nt], 0,0,0);
      o1[nt] = __builtin_amdgcn_mfma_f32_16x16x32_bf16(pf, v1,    o1[nt], 0,0,0);
      o2[nt] = __builtin_amdgcn_mfma_f32_16x16x32_bf16(pf, vones, o2[nt], 0,0,0);  // row sums
    }
  }

  #pragma unroll
  for (int nt=0;nt<4;nt++){
    #pragma unroll
    for (int i=0;i<4;i++){
      float ssum = __shfl(o2[nt][i], l & 48);    // (m=q4*4+i, n=0) lives at lane q4*16
      float inv = RCPF(ssum);
      long node = nb + nt*16 + q4*4 + i;
      q[node*H + h*HD + lc]      = rnd_bf16(o0[nt][i]*inv);
      q[node*H + h*HD + 16 + lc] = rnd_bf16(o1[nt][i]*inv);
    }
  }
}

// ---------------- fused out-proj + mean-pool + classifier: block = 128 nodes = 2 graphs ----------------
__global__ __launch_bounds__(256) void k_gemm_out(const unsigned short* __restrict__ A,
      const float* __restrict__ Bsrc, const float* __restrict__ bias,
      const float* __restrict__ W1, const float* __restrict__ b1,
      const float* __restrict__ W2, const float* __restrict__ b2, float* __restrict__ out){
  __shared__ unsigned short Bt[128][136];
  __shared__ float pools[4][128];
  __shared__ float pooled[2][128];
  int tid = threadIdx.x;
  long rowBase = (long)blockIdx.x * 128;
  int w = tid >> 6, l = tid & 63;
  int lc = l & 15, q4 = l >> 4;

  for (int i = tid; i < 4096; i += 256){     // B = out_W^T: B(k,c) = Bsrc[c*128+k]
    int c = i >> 5, seg = i & 31;
    float4 v = *(const float4*)(Bsrc + (long)c*128 + seg*4);
    uint2 p; p.x = pk_bf16(v.x, v.y); p.y = pk_bf16(v.z, v.w);
    *(uint2*)&Bt[c][seg*4] = p;
  }

  short8 af[2][4];
  #pragma unroll
  for (int rt=0;rt<2;rt++){
    long row = rowBase + w*32 + rt*16 + lc;
    #pragma unroll
    for (int kc=0;kc<4;kc++)
      af[rt][kc] = *(const short8*)(A + row*128 + kc*32 + q4*8);
  }

  f32x4 acc[2][8];
  #pragma unroll
  for (int rt=0;rt<2;rt++)
    #pragma unroll
    for (int ct=0;ct<8;ct++) acc[rt][ct] = (f32x4){0.f,0.f,0.f,0.f};

  __syncthreads();

  #pragma unroll
  for (int kc=0;kc<4;kc++){
    #pragma unroll
    for (int ct=0;ct<8;ct++){
      short8 bf = *(const short8*)&Bt[ct*16 + lc][kc*32 + q4*8];
      acc[0][ct] = __builtin_amdgcn_mfma_f32_16x16x32_bf16(af[0][kc], bf, acc[0][ct], 0,0,0);
      acc[1][ct] = __builtin_amdgcn_mfma_f32_16x16x32_bf16(af[1][kc], bf, acc[1][ct], 0,0,0);
    }
  }

  // per-wave column sums over its 32 rows (graph = w>>1), then cross-quad reduce
  #pragma unroll
  for (int ct=0;ct<8;ct++){
    float ps = acc[0][ct][0]+acc[0][ct][1]+acc[0][ct][2]+acc[0][ct][3]
             + acc[1][ct][0]+acc[1][ct][1]+acc[1][ct][2]+acc[1][ct][3];
    ps += __shfl_xor(ps, 16);
    ps += __shfl_xor(ps, 32);
    if (q4 == 0) pools[w][ct*16 + lc] = ps;
  }
  __syncthreads();

  if (tid < 128){
    int c = tid;
    pooled[0][c] = (pools[0][c] + pools[1][c]) * (1.0f/64.0f) + bias[c];
    pooled[1][c] = (pools[2][c] + pools[3][c]) * (1.0f/64.0f) + bias[c];
  }
  __syncthreads();

  if (tid < 128){
    int g = tid >> 6, tp = tid & 63;
    float hh = b1[tp];
    for (int c=0;c<128;c++) hh = fmaf(pooled[g][c], W1[c*64 + tp], hh);
    hh = fmaxf(hh, 0.0f);
    float v = hh * W2[tp];
    #pragma unroll
    for (int off=32; off>0; off>>=1) v += __shfl_down(v, off);
    if (tp == 0) out[blockIdx.x*2 + g] = v + b2[0];
  }
}

extern "C" void kernel_launch(void* const* d_in, const int* in_sizes, int n_in,
                              void* d_out, int out_size, void* d_ws, size_t ws_size,
                              hipStream_t stream){
  const float* x     = (const float*)d_in[0];
  const int*   ei    = (const int*)d_in[1];
  const float* perres= (const float*)d_in[3];
  const float* W0 = (const float*)d_in[4];
  const float* b0 = (const float*)d_in[5];
  const float* W1 = (const float*)d_in[6];  const float* b1 = (const float*)d_in[7];
  const float* W2 = (const float*)d_in[8];  const float* b2 = (const float*)d_in[9];
  const float* bng = (const float*)d_in[10]; const float* bnb = (const float*)d_in[11];
  const float* bnm = (const float*)d_in[12]; const float* bnv = (const float*)d_in[13];
  const float* resW = (const float*)d_in[14]; const float* resb = (const float*)d_in[15];
  const float* inW  = (const float*)d_in[16]; const float* inb  = (const float*)d_in[17];
  const float* outW = (const float*)d_in[18]; const float* outb = (const float*)d_in[19];
  const float* cW1 = (const float*)d_in[20]; const float* cb1 = (const float*)d_in[21];
  const float* cW2 = (const float*)d_in[22]; const float* cb2 = (const float*)d_in[23];
  float* out = (float*)d_out;

  char* ws = (char*)d_ws;
  size_t off = 0;
  auto alloc = [&](size_t bytes) -> char* {
    char* p = ws + off;
    off += (bytes + 255) & ~(size_t)255;
    return p;
  };
  float* dinv    = (float*)alloc((size_t)N_NODES*4);
  int*   cnt     = (int*)  alloc((size_t)N_NODES*4);
  int*   cursor  = (int*)  alloc((size_t)N_NODES*4);
  int*   csr_off = (int*)  alloc((size_t)(N_NODES+1)*4);
  int*   csr_src = (int*)  alloc((size_t)N_EDGES*4);
  float* csr_w   = (float*)alloc((size_t)N_EDGES*4);
  unsigned short* mb  = (unsigned short*)alloc((size_t)N_NODES*H*2);  // bf16: m / q / o
  unsigned short* hb  = (unsigned short*)alloc((size_t)N_NODES*H*2);  // bf16: h
  unsigned short* resbuf = (unsigned short*)alloc((size_t)R_RES*H*2); // bf16
  float* Kbuf    = (float*)alloc((size_t)R_RES*H*4);
  float* Vbuf    = (float*)alloc((size_t)R_RES*H*4);
  if (off > ws_size) return;

  const int* srcI = ei;
  const int* dstI = ei + N_EDGES;

  // CSR build
  hipMemsetAsync(cnt, 0, (size_t)N_NODES*4, stream);
  k_count<<<N_EDGES/256, 256, 0, stream>>>(dstI, cnt, N_EDGES);
  k_scan<<<1, 1024, 0, stream>>>(cnt, csr_off, cursor, dinv);
  k_fill<<<N_EDGES/256, 256, 0, stream>>>(srcI, dstI, dinv, cursor, csr_src, csr_w, N_EDGES);

  const int NB = N_NODES/128;
  // GCN: layer 0 (K=7 VALU), layers 1/2 via MFMA
  k_lin0<<<N_NODES/4, 256, 0, stream>>>(x, W0, mb);
  k_agg<<<N_NODES/4, 256, 0, stream>>>(mb, csr_off, csr_src, csr_w, dinv, b0, bng,     bnb,     bnm,     bnv,     hb);
  k_gemm_mfma<<<NB, 256, 0, stream>>>(hb, W1, nullptr, mb, 0, 0, 1.0f);
  k_agg<<<N_NODES/4, 256, 0, stream>>>(mb, csr_off, csr_src, csr_w, dinv, b1, bng+128, bnb+128, bnm+128, bnv+128, hb);
  k_gemm_mfma<<<NB, 256, 0, stream>>>(hb, W2, nullptr, mb, 0, 0, 1.0f);
  k_agg<<<N_NODES/4, 256, 0, stream>>>(mb, csr_off, csr_src, csr_w, dinv, b2, bng+256, bnb+256, bnm+256, bnv+256, hb);

  // residue chain: res-proj (K=25, fp32 math, bf16 out) then K/V via MFMA (fp32 out)
  k_gemm<<<R_RES/128, 256, 0, stream>>>(perres, resW, resb, resbuf, 25, 0, 1);
  k_gemm_mfma<<<R_RES/128, 256, 0, stream>>>(resbuf, inW + 128*128, inb + 128, Kbuf, 1, 1, 1.0f);
  k_gemm_mfma<<<R_RES/128, 256, 0, stream>>>(resbuf, inW + 256*128, inb + 256, Vbuf, 1, 1, 1.0f);

  // q projection with folded softmax scale (log2e/sqrt(32)), then fused attention
  k_gemm_mfma<<<NB, 256, 0, stream>>>(hb, inW, inb, mb, 1, 0, 0.25503489f);
  dim3 agrid(N_NODES/256, NH);
  k_attn<<<agrid, 256, 0, stream>>>(mb, Kbuf, Vbuf);

  // fused out-proj + mean pool + classifier
  k_gemm_out<<<NB, 256, 0, stream>>>(mb, outW, outb, cW1, cb1, cW2, cb2, out);
}

// Round 5
// 458.764 us; speedup vs baseline: 1.9620x; 1.0515x over previous
//
#include <hip/hip_runtime.h>
#include <math.h>

#define N_NODES 65536
#define N_EDGES 524288
#define N_GRAPHS 1024
#define H 128
#define R_RES 512
#define NH 4
#define HD 32
#define D_IN 7
#define EPS 1e-5f

typedef __attribute__((ext_vector_type(8))) short short8;
typedef __attribute__((ext_vector_type(4))) float f32x4;
typedef __attribute__((ext_vector_type(4))) unsigned uint4v;
typedef __attribute__((ext_vector_type(4))) unsigned short us4;

#if __has_builtin(__builtin_amdgcn_exp2f)
#define EXP2F __builtin_amdgcn_exp2f
#else
#define EXP2F exp2f
#endif
#if __has_builtin(__builtin_amdgcn_rcpf)
#define RCPF __builtin_amdgcn_rcpf
#else
#define RCPF(x) (1.0f/(x))
#endif

// round-half-up bf16 (1 add; max 0.5ulp)
__device__ __forceinline__ unsigned short rnd_bf16(float f){
  return (unsigned short)((__builtin_bit_cast(unsigned, f) + 0x8000u) >> 16);
}
// pack two floats -> bf16x2 in one v_perm
__device__ __forceinline__ unsigned pk_bf16(float lo, float hi){
  unsigned a = __builtin_bit_cast(unsigned, lo) + 0x8000u;
  unsigned b = __builtin_bit_cast(unsigned, hi) + 0x8000u;
  return __builtin_amdgcn_perm(b, a, 0x07060302u);
}
__device__ __forceinline__ float bflo(unsigned u){ return __builtin_bit_cast(float, u << 16); }
__device__ __forceinline__ float bfhi(unsigned u){ return __builtin_bit_cast(float, u & 0xFFFF0000u); }

// ---------------- CSR build ----------------
__global__ __launch_bounds__(256) void k_count(const int* __restrict__ dst, int* __restrict__ cnt, int E){
  int e = blockIdx.x*256 + threadIdx.x;
  if (e < E) atomicAdd(&cnt[dst[e]], 1);
}

__global__ __launch_bounds__(1024) void k_scan(const int* __restrict__ cnt, int* __restrict__ csr_off,
                                               int* __restrict__ cursor, float* __restrict__ dinv){
  __shared__ int part[1024];
  int t = threadIdx.x;
  int base = t*64;
  int s = 0;
  for (int j=0;j<64;j++) s += cnt[base+j];
  part[t] = s;
  __syncthreads();
  for (int off=1; off<1024; off<<=1){
    int v = (t >= off) ? part[t-off] : 0;
    __syncthreads();
    part[t] += v;
    __syncthreads();
  }
  int run = (t == 0) ? 0 : part[t-1];
  for (int j=0;j<64;j++){
    int i = base+j;
    int c = cnt[i];
    csr_off[i] = run;
    cursor[i] = run;
    dinv[i] = rsqrtf(1.0f + (float)c);
    run += c;
  }
  if (t == 0) csr_off[N_NODES] = N_EDGES;
}

__global__ __launch_bounds__(256) void k_fill(const int* __restrict__ src, const int* __restrict__ dst,
      const float* __restrict__ dinv, int* __restrict__ cursor,
      int* __restrict__ csr_src, float* __restrict__ csr_w, int E){
  int e = blockIdx.x*256 + threadIdx.x;
  if (e >= E) return;
  int s = src[e], d = dst[e];
  int p = atomicAdd(&cursor[d], 1);
  csr_src[p] = s;
  csr_w[p] = dinv[s]*dinv[d];
}

// ---------------- layer-0: m = x @ W0, K=7, bf16 out ----------------
__global__ __launch_bounds__(256) void k_lin0(const float* __restrict__ x, const float* __restrict__ W0,
                                              unsigned short* __restrict__ out){
  int gid = blockIdx.x*256 + threadIdx.x;
  int l = threadIdx.x & 63;
  int n = __builtin_amdgcn_readfirstlane(gid >> 6);
  float a0 = 0.0f, a1 = 0.0f;
  #pragma unroll
  for (int k=0;k<D_IN;k++){
    float xv = x[(long)n*D_IN + k];
    float2 wv = *(const float2*)(W0 + k*H + 2*l);
    a0 = fmaf(xv, wv.x, a0); a1 = fmaf(xv, wv.y, a1);
  }
  *(unsigned*)(out + (long)n*H + 2*l) = pk_bf16(a0, a1);
}

// ---------------- bf16 MFMA GEMM: C[M,128] = A_bf16[M,128] @ B (+bias) ----------------
// outMode: 0 = bf16 row-major, 1 = fp32 row-major, 2 = bf16 transposed C^T[col*512+row]
__global__ __launch_bounds__(256) void k_gemm_mfma(const unsigned short* __restrict__ A,
      const float* __restrict__ Bsrc, const float* __restrict__ bias, void* __restrict__ Cout,
      int transB, int outMode){
  __shared__ unsigned short Bt[128][136];   // Bt[c][k], k-contiguous
  int tid = threadIdx.x;
  long rowBase = (long)blockIdx.x * 128;
  int w = tid >> 6, l = tid & 63;
  int lc = l & 15, q4 = l >> 4;

  if (transB){
    for (int i = tid; i < 4096; i += 256){
      int c = i >> 5, seg = i & 31;
      float4 v = *(const float4*)(Bsrc + (long)c*128 + seg*4);
      uint2 p; p.x = pk_bf16(v.x, v.y); p.y = pk_bf16(v.z, v.w);
      *(uint2*)&Bt[c][seg*4] = p;
    }
  } else {
    for (int i = tid; i < 4096; i += 256){
      int k = i >> 5, seg = i & 31;
      float4 v = *(const float4*)(Bsrc + (long)k*128 + seg*4);
      Bt[seg*4+0][k] = rnd_bf16(v.x); Bt[seg*4+1][k] = rnd_bf16(v.y);
      Bt[seg*4+2][k] = rnd_bf16(v.z); Bt[seg*4+3][k] = rnd_bf16(v.w);
    }
  }

  short8 af[2][4];
  #pragma unroll
  for (int rt=0;rt<2;rt++){
    long row = rowBase + w*32 + rt*16 + lc;
    #pragma unroll
    for (int kc=0;kc<4;kc++)
      af[rt][kc] = *(const short8*)(A + row*128 + kc*32 + q4*8);
  }

  f32x4 acc[2][8];
  #pragma unroll
  for (int rt=0;rt<2;rt++)
    #pragma unroll
    for (int ct=0;ct<8;ct++) acc[rt][ct] = (f32x4){0.f,0.f,0.f,0.f};

  __syncthreads();

  #pragma unroll
  for (int kc=0;kc<4;kc++){
    #pragma unroll
    for (int ct=0;ct<8;ct++){
      short8 bf = *(const short8*)&Bt[ct*16 + lc][kc*32 + q4*8];
      acc[0][ct] = __builtin_amdgcn_mfma_f32_16x16x32_bf16(af[0][kc], bf, acc[0][ct], 0,0,0);
      acc[1][ct] = __builtin_amdgcn_mfma_f32_16x16x32_bf16(af[1][kc], bf, acc[1][ct], 0,0,0);
    }
  }

  float bv[8];
  #pragma unroll
  for (int ct=0;ct<8;ct++) bv[ct] = bias ? bias[ct*16 + lc] : 0.0f;
  #pragma unroll
  for (int rt=0;rt<2;rt++){
    #pragma unroll
    for (int ct=0;ct<8;ct++){
      int col = ct*16 + lc;
      float vv[4];
      #pragma unroll
      for (int i=0;i<4;i++) vv[i] = acc[rt][ct][i] + bv[ct];
      long row0 = rowBase + w*32 + rt*16 + q4*4;
      if (outMode == 0){
        #pragma unroll
        for (int i=0;i<4;i++) ((unsigned short*)Cout)[(row0+i)*128 + col] = rnd_bf16(vv[i]);
      } else if (outMode == 1){
        #pragma unroll
        for (int i=0;i<4;i++) ((float*)Cout)[(row0+i)*128 + col] = vv[i];
      } else {
        us4 p = {rnd_bf16(vv[0]), rnd_bf16(vv[1]), rnd_bf16(vv[2]), rnd_bf16(vv[3])};
        *(us4*)((unsigned short*)Cout + (long)col*512 + row0) = p;   // C^T for V-transpose
      }
    }
  }
}

// ---------------- GCN aggregation + bias + BN + ReLU, bf16 in/out ----------------
__global__ __launch_bounds__(256) void k_agg(const unsigned short* __restrict__ m, const int* __restrict__ csr_off,
      const int* __restrict__ csr_src, const float* __restrict__ csr_w, const float* __restrict__ dinv,
      const float* __restrict__ b, const float* __restrict__ gamma, const float* __restrict__ beta,
      const float* __restrict__ mean, const float* __restrict__ var, unsigned short* __restrict__ out){
  int gt = blockIdx.x*256 + threadIdx.x;
  int lane = threadIdx.x & 63;
  int n = __builtin_amdgcn_readfirstlane(gt >> 6);
  int c = lane*2;
  float dn = dinv[n];
  float sn = dn*dn;
  unsigned ua = *(const unsigned*)(m + (long)n*H + c);
  float ax = bflo(ua)*sn, ay = bfhi(ua)*sn;
  int e0 = csr_off[n], e1 = csr_off[n+1];
  int e = e0;
  for (; e + 2 <= e1; e += 2){
    int s0 = csr_src[e],   s1 = csr_src[e+1];
    float w0 = csr_w[e],   w1 = csr_w[e+1];
    unsigned u0 = *(const unsigned*)(m + (long)s0*H + c);
    unsigned u1 = *(const unsigned*)(m + (long)s1*H + c);
    ax = fmaf(bflo(u0), w0, ax); ay = fmaf(bfhi(u0), w0, ay);
    ax = fmaf(bflo(u1), w1, ax); ay = fmaf(bfhi(u1), w1, ay);
  }
  if (e < e1){
    int s0 = csr_src[e]; float w0 = csr_w[e];
    unsigned u0 = *(const unsigned*)(m + (long)s0*H + c);
    ax = fmaf(bflo(u0), w0, ax); ay = fmaf(bfhi(u0), w0, ay);
  }
  float rx, ry;
  {
    float sc = gamma[c] * rsqrtf(var[c] + EPS);
    rx = fmaxf(sc*(ax + b[c] - mean[c]) + beta[c], 0.0f);
  }
  {
    int c1 = c+1;
    float sc = gamma[c1] * rsqrtf(var[c1] + EPS);
    ry = fmaxf(sc*(ay + b[c1] - mean[c1]) + beta[c1], 0.0f);
  }
  *(unsigned*)(out + (long)n*H + c) = pk_bf16(rx, ry);
}

// ---------------- fp32 GEMM (res projection, K=25), bf16 out ----------------
__global__ __launch_bounds__(256,2) void k_gemm(const float* __restrict__ A, const float* __restrict__ B,
      const float* __restrict__ bias, void* __restrict__ C, int K, int transB, int outBf16){
  __shared__ float Bs[128][132];
  __shared__ float As[16][128];
  int tid = threadIdx.x;
  long rowBase = (long)blockIdx.x * 128;

  if (!transB){
    for (int idx = tid; idx < 128*128; idx += 256){
      int k = idx >> 7, c = idx & 127;
      Bs[k][c] = (k < K) ? B[(long)k*128 + c] : 0.0f;
    }
  } else {
    for (int idx = tid; idx < 128*128; idx += 256){
      int c = idx >> 7, k = idx & 127;
      Bs[k][c] = (k < K) ? B[(long)c*K + k] : 0.0f;
    }
  }

  float acc[8][8];
  #pragma unroll
  for (int i=0;i<8;i++)
    #pragma unroll
    for (int j=0;j<8;j++) acc[i][j] = 0.0f;

  int rg = tid >> 4, cg = tid & 15;
  int r0 = rg*8, c0 = cg*8;
  int srow = tid >> 1, skoff = (tid & 1)*8;
  const bool fast = ((K & 15) == 0);

  for (int k0 = 0; k0 < K; k0 += 16){
    __syncthreads();
    const float* ap = A + (rowBase + srow)*K + k0 + skoff;
    if (fast){
      float4 v0 = *(const float4*)(ap);
      float4 v1 = *(const float4*)(ap + 4);
      As[skoff+0][srow] = v0.x; As[skoff+1][srow] = v0.y;
      As[skoff+2][srow] = v0.z; As[skoff+3][srow] = v0.w;
      As[skoff+4][srow] = v1.x; As[skoff+5][srow] = v1.y;
      As[skoff+6][srow] = v1.z; As[skoff+7][srow] = v1.w;
    } else {
      #pragma unroll
      for (int j=0;j<8;j++){
        int kk = k0 + skoff + j;
        As[skoff+j][srow] = (kk < K) ? ap[j] : 0.0f;
      }
    }
    __syncthreads();
    #pragma unroll
    for (int k=0;k<16;k++){
      float4 a0 = *(const float4*)(&As[k][r0]);
      float4 a1 = *(const float4*)(&As[k][r0+4]);
      float4 b0 = *(const float4*)(&Bs[k0+k][c0]);
      float4 b1 = *(const float4*)(&Bs[k0+k][c0+4]);
      float a[8] = {a0.x,a0.y,a0.z,a0.w,a1.x,a1.y,a1.z,a1.w};
      float b[8] = {b0.x,b0.y,b0.z,b0.w,b1.x,b1.y,b1.z,b1.w};
      #pragma unroll
      for (int i=0;i<8;i++)
        #pragma unroll
        for (int j=0;j<8;j++)
          acc[i][j] = fmaf(a[i], b[j], acc[i][j]);
    }
  }

  #pragma unroll
  for (int i=0;i<8;i++){
    float o[8];
    #pragma unroll
    for (int j=0;j<8;j++) o[j] = acc[i][j] + (bias ? bias[c0+j] : 0.0f);
    long row = rowBase + r0 + i;
    if (outBf16){
      uint4v p;
      p.x = pk_bf16(o[0],o[1]); p.y = pk_bf16(o[2],o[3]);
      p.z = pk_bf16(o[4],o[5]); p.w = pk_bf16(o[6],o[7]);
      *(uint4v*)((unsigned short*)C + row*128 + c0) = p;
    } else {
      float* cp = (float*)C + row*128 + c0;
      *(float4*)cp = (float4){o[0],o[1],o[2],o[3]};
      *(float4*)(cp+4) = (float4){o[4],o[5],o[6],o[7]};
    }
  }
}

// ---------------- fused q-proj + flash cross-attention ----------------
// block = 256 nodes x 1 head; K/V fragments read straight from global bf16
// (Kbf [512][128], Vt [128][512] — shared by all blocks, L1/L2-resident).
// LDS: wave-private 5120B chunk (q staging, later overlaid by exp(S) buffer).
__global__ __launch_bounds__(256,3) void k_attn(const unsigned short* __restrict__ hb,
      const float* __restrict__ inW, const float* __restrict__ inb,
      const unsigned short* __restrict__ Kbf, const unsigned short* __restrict__ Vt,
      unsigned short* __restrict__ obuf){
  __shared__ __align__(16) char smem[4*5120];
  int tid = threadIdx.x;
  int h = blockIdx.y;
  int w = tid >> 6, l = tid & 63;
  int lc = l & 15, q4 = l >> 4;
  unsigned short* qsw = (unsigned short*)(smem + w*5120);  // [64][40] bf16
  float* Pfw = (float*)(smem + w*5120);                    // [16][36] f32 overlay (after qf read)

  long nb = (long)blockIdx.x*256 + w*64;
  const float scale = 0.25503489f;   // log2(e)/sqrt(32): exp2 after folded scale

  // ---- q-projection for this wave's 64 nodes: q = h @ Wq^T + bq, scaled ----
  {
    short8 bqf[2][4];
    #pragma unroll
    for (int ct=0;ct<2;ct++){
      int c = h*32 + ct*16 + lc;
      #pragma unroll
      for (int kc=0;kc<4;kc++){
        const float* wp = inW + (long)c*128 + kc*32 + q4*8;
        float4 x0 = *(const float4*)wp;
        float4 x1 = *(const float4*)(wp+4);
        uint4v p; p.x = pk_bf16(x0.x,x0.y); p.y = pk_bf16(x0.z,x0.w);
        p.z = pk_bf16(x1.x,x1.y); p.w = pk_bf16(x1.z,x1.w);
        bqf[ct][kc] = __builtin_bit_cast(short8, p);
      }
    }
    float bqv[2] = { inb[h*32 + lc], inb[h*32 + 16 + lc] };
    #pragma unroll
    for (int nt=0;nt<4;nt++){
      short8 af[4];
      #pragma unroll
      for (int kc=0;kc<4;kc++)
        af[kc] = *(const short8*)(hb + (nb + nt*16 + lc)*128 + kc*32 + q4*8);
      #pragma unroll
      for (int ct=0;ct<2;ct++){
        f32x4 qa = {0.f,0.f,0.f,0.f};
        #pragma unroll
        for (int kc=0;kc<4;kc++)
          qa = __builtin_amdgcn_mfma_f32_16x16x32_bf16(af[kc], bqf[ct][kc], qa, 0,0,0);
        #pragma unroll
        for (int i=0;i<4;i++)   // C layout: row=q4*4+i, col=ct*16+lc
          qsw[(nt*16 + q4*4 + i)*40 + ct*16 + lc] = rnd_bf16((qa[i] + bqv[ct]) * scale);
      }
    }
  }
  // C->A layout turn (wave-private LDS, DS ops in order: no barrier)
  short8 qf[4];
  #pragma unroll
  for (int nt=0;nt<4;nt++)
    qf[nt] = *(const short8*)&qsw[(nt*16 + lc)*40 + q4*8];

  f32x4 o0[4], o1[4];
  float ps[4][4];
  #pragma unroll
  for (int nt=0;nt<4;nt++){
    o0[nt] = (f32x4){0.f,0.f,0.f,0.f};
    o1[nt] = (f32x4){0.f,0.f,0.f,0.f};
    #pragma unroll
    for (int i=0;i<4;i++) ps[nt][i] = 0.0f;
  }

  const unsigned short* Kp = Kbf + (long)lc*128 + h*32 + q4*8;      // B-frag: n=res, k=dim
  const unsigned short* Vp = Vt + ((long)(h*32 + lc))*512 + q4*8;   // B-frag: n=dim, k=res

  for (int ch = 0; ch < 16; ch++){
    short8 kf0 = *(const short8*)(Kp + (long)(ch*32)*128);
    short8 kf1 = *(const short8*)(Kp + (long)(ch*32+16)*128);
    short8 v0  = *(const short8*)(Vp + ch*32);
    short8 v1  = *(const short8*)(Vp + 16*512 + ch*32);
    #pragma unroll
    for (int nt=0;nt<4;nt++){
      f32x4 z = {0.f,0.f,0.f,0.f};
      f32x4 sa = __builtin_amdgcn_mfma_f32_16x16x32_bf16(qf[nt], kf0, z, 0,0,0);
      f32x4 sb = __builtin_amdgcn_mfma_f32_16x16x32_bf16(qf[nt], kf1, z, 0,0,0);
      float ea[4], eb[4];
      #pragma unroll
      for (int i=0;i<4;i++){ ea[i] = EXP2F(sa[i]); eb[i] = EXP2F(sb[i]); }
      #pragma unroll
      for (int i=0;i<4;i++){
        Pfw[(q4*4+i)*36 + lc]      = ea[i];
        Pfw[(q4*4+i)*36 + 16 + lc] = eb[i];
        ps[nt][i] += ea[i] + eb[i];
      }
      float4 pa = *(const float4*)&Pfw[lc*36 + q4*8];
      float4 pb = *(const float4*)&Pfw[lc*36 + q4*8 + 4];
      uint4v pk4;
      pk4.x = pk_bf16(pa.x, pa.y); pk4.y = pk_bf16(pa.z, pa.w);
      pk4.z = pk_bf16(pb.x, pb.y); pk4.w = pk_bf16(pb.z, pb.w);
      short8 pf = __builtin_bit_cast(short8, pk4);
      o0[nt] = __builtin_amdgcn_mfma_f32_16x16x32_bf16(pf, v0, o0[nt], 0,0,0);
      o1[nt] = __builtin_amdgcn_mfma_f32_16x16x32_bf16(pf, v1, o1[nt], 0,0,0);
    }
  }

  #pragma unroll
  for (int nt=0;nt<4;nt++){
    #pragma unroll
    for (int i=0;i<4;i++){
      float s = ps[nt][i];
      s += __shfl_xor(s, 1); s += __shfl_xor(s, 2);
      s += __shfl_xor(s, 4); s += __shfl_xor(s, 8);
      float inv = RCPF(s);
      long node = nb + nt*16 + q4*4 + i;
      obuf[node*128 + h*32 + lc]      = rnd_bf16(o0[nt][i]*inv);
      obuf[node*128 + h*32 + 16 + lc] = rnd_bf16(o1[nt][i]*inv);
    }
  }
}

// ---------------- fused out-proj + mean-pool + classifier: block = 128 nodes = 2 graphs ----------------
__global__ __launch_bounds__(256) void k_gemm_out(const unsigned short* __restrict__ A,
      const float* __restrict__ Bsrc, const float* __restrict__ bias,
      const float* __restrict__ W1, const float* __restrict__ b1,
      const float* __restrict__ W2, const float* __restrict__ b2, float* __restrict__ out){
  __shared__ unsigned short Bt[128][136];
  __shared__ float pools[4][128];
  __shared__ float pooled[2][128];
  int tid = threadIdx.x;
  long rowBase = (long)blockIdx.x * 128;
  int w = tid >> 6, l = tid & 63;
  int lc = l & 15, q4 = l >> 4;

  for (int i = tid; i < 4096; i += 256){
    int c = i >> 5, seg = i & 31;
    float4 v = *(const float4*)(Bsrc + (long)c*128 + seg*4);
    uint2 p; p.x = pk_bf16(v.x, v.y); p.y = pk_bf16(v.z, v.w);
    *(uint2*)&Bt[c][seg*4] = p;
  }

  short8 af[2][4];
  #pragma unroll
  for (int rt=0;rt<2;rt++){
    long row = rowBase + w*32 + rt*16 + lc;
    #pragma unroll
    for (int kc=0;kc<4;kc++)
      af[rt][kc] = *(const short8*)(A + row*128 + kc*32 + q4*8);
  }

  f32x4 acc[2][8];
  #pragma unroll
  for (int rt=0;rt<2;rt++)
    #pragma unroll
    for (int ct=0;ct<8;ct++) acc[rt][ct] = (f32x4){0.f,0.f,0.f,0.f};

  __syncthreads();

  #pragma unroll
  for (int kc=0;kc<4;kc++){
    #pragma unroll
    for (int ct=0;ct<8;ct++){
      short8 bf = *(const short8*)&Bt[ct*16 + lc][kc*32 + q4*8];
      acc[0][ct] = __builtin_amdgcn_mfma_f32_16x16x32_bf16(af[0][kc], bf, acc[0][ct], 0,0,0);
      acc[1][ct] = __builtin_amdgcn_mfma_f32_16x16x32_bf16(af[1][kc], bf, acc[1][ct], 0,0,0);
    }
  }

  #pragma unroll
  for (int ct=0;ct<8;ct++){
    float ps = acc[0][ct][0]+acc[0][ct][1]+acc[0][ct][2]+acc[0][ct][3]
             + acc[1][ct][0]+acc[1][ct][1]+acc[1][ct][2]+acc[1][ct][3];
    ps += __shfl_xor(ps, 16);
    ps += __shfl_xor(ps, 32);
    if (q4 == 0) pools[w][ct*16 + lc] = ps;
  }
  __syncthreads();

  if (tid < 128){
    int c = tid;
    pooled[0][c] = (pools[0][c] + pools[1][c]) * (1.0f/64.0f) + bias[c];
    pooled[1][c] = (pools[2][c] + pools[3][c]) * (1.0f/64.0f) + bias[c];
  }
  __syncthreads();

  if (tid < 128){
    int g = tid >> 6, tp = tid & 63;
    float hh = b1[tp];
    for (int c=0;c<128;c++) hh = fmaf(pooled[g][c], W1[c*64 + tp], hh);
    hh = fmaxf(hh, 0.0f);
    float v = hh * W2[tp];
    #pragma unroll
    for (int off=32; off>0; off>>=1) v += __shfl_down(v, off);
    if (tp == 0) out[blockIdx.x*2 + g] = v + b2[0];
  }
}

extern "C" void kernel_launch(void* const* d_in, const int* in_sizes, int n_in,
                              void* d_out, int out_size, void* d_ws, size_t ws_size,
                              hipStream_t stream){
  const float* x     = (const float*)d_in[0];
  const int*   ei    = (const int*)d_in[1];
  const float* perres= (const float*)d_in[3];
  const float* W0 = (const float*)d_in[4];
  const float* b0 = (const float*)d_in[5];
  const float* W1 = (const float*)d_in[6];  const float* b1 = (const float*)d_in[7];
  const float* W2 = (const float*)d_in[8];  const float* b2 = (const float*)d_in[9];
  const float* bng = (const float*)d_in[10]; const float* bnb = (const float*)d_in[11];
  const float* bnm = (const float*)d_in[12]; const float* bnv = (const float*)d_in[13];
  const float* resW = (const float*)d_in[14]; const float* resb = (const float*)d_in[15];
  const float* inW  = (const float*)d_in[16]; const float* inb  = (const float*)d_in[17];
  const float* outW = (const float*)d_in[18]; const float* outb = (const float*)d_in[19];
  const float* cW1 = (const float*)d_in[20]; const float* cb1 = (const float*)d_in[21];
  const float* cW2 = (const float*)d_in[22]; const float* cb2 = (const float*)d_in[23];
  float* out = (float*)d_out;

  char* ws = (char*)d_ws;
  size_t off = 0;
  auto alloc = [&](size_t bytes) -> char* {
    char* p = ws + off;
    off += (bytes + 255) & ~(size_t)255;
    return p;
  };
  float* dinv    = (float*)alloc((size_t)N_NODES*4);
  int*   cnt     = (int*)  alloc((size_t)N_NODES*4);
  int*   cursor  = (int*)  alloc((size_t)N_NODES*4);
  int*   csr_off = (int*)  alloc((size_t)(N_NODES+1)*4);
  int*   csr_src = (int*)  alloc((size_t)N_EDGES*4);
  float* csr_w   = (float*)alloc((size_t)N_EDGES*4);
  unsigned short* mb  = (unsigned short*)alloc((size_t)N_NODES*H*2);  // bf16: m / o
  unsigned short* hb  = (unsigned short*)alloc((size_t)N_NODES*H*2);  // bf16: h
  unsigned short* resbuf = (unsigned short*)alloc((size_t)R_RES*H*2); // bf16
  unsigned short* Kbf = (unsigned short*)alloc((size_t)R_RES*H*2);    // bf16 K [512][128]
  unsigned short* Vtb = (unsigned short*)alloc((size_t)H*R_RES*2);    // bf16 V^T [128][512]
  if (off > ws_size) return;

  const int* srcI = ei;
  const int* dstI = ei + N_EDGES;

  // CSR build
  hipMemsetAsync(cnt, 0, (size_t)N_NODES*4, stream);
  k_count<<<N_EDGES/256, 256, 0, stream>>>(dstI, cnt, N_EDGES);
  k_scan<<<1, 1024, 0, stream>>>(cnt, csr_off, cursor, dinv);
  k_fill<<<N_EDGES/256, 256, 0, stream>>>(srcI, dstI, dinv, cursor, csr_src, csr_w, N_EDGES);

  const int NB = N_NODES/128;
  // GCN: layer 0 (K=7 VALU), layers 1/2 via MFMA
  k_lin0<<<N_NODES/4, 256, 0, stream>>>(x, W0, mb);
  k_agg<<<N_NODES/4, 256, 0, stream>>>(mb, csr_off, csr_src, csr_w, dinv, b0, bng,     bnb,     bnm,     bnv,     hb);
  k_gemm_mfma<<<NB, 256, 0, stream>>>(hb, W1, nullptr, mb, 0, 0);
  k_agg<<<N_NODES/4, 256, 0, stream>>>(mb, csr_off, csr_src, csr_w, dinv, b1, bng+128, bnb+128, bnm+128, bnv+128, hb);
  k_gemm_mfma<<<NB, 256, 0, stream>>>(hb, W2, nullptr, mb, 0, 0);
  k_agg<<<N_NODES/4, 256, 0, stream>>>(mb, csr_off, csr_src, csr_w, dinv, b2, bng+256, bnb+256, bnm+256, bnv+256, hb);

  // residue chain: res-proj (K=25, fp32 math, bf16 out); K bf16 row-major; V bf16 transposed
  k_gemm<<<R_RES/128, 256, 0, stream>>>(perres, resW, resb, resbuf, 25, 0, 1);
  k_gemm_mfma<<<R_RES/128, 256, 0, stream>>>(resbuf, inW + 128*128, inb + 128, Kbf, 1, 0);
  k_gemm_mfma<<<R_RES/128, 256, 0, stream>>>(resbuf, inW + 256*128, inb + 256, Vtb, 1, 2);

  // fused q-proj + attention (o -> mb)
  dim3 agrid(N_NODES/256, NH);
  k_attn<<<agrid, 256, 0, stream>>>(hb, inW, inb, Kbf, Vtb, mb);

  // fused out-proj + mean pool + classifier
  k_gemm_out<<<NB, 256, 0, stream>>>(mb, outW, outb, cW1, cb1, cW2, cb2, out);
}

// Round 6
// 416.179 us; speedup vs baseline: 2.1628x; 1.1023x over previous
//
#include <hip/hip_runtime.h>
#include <math.h>

#define N_NODES 65536
#define N_EDGES 524288
#define N_GRAPHS 1024
#define H 128
#define R_RES 512
#define NH 4
#define HD 32
#define D_IN 7
#define EPS 1e-5f

typedef __attribute__((ext_vector_type(8))) short short8;
typedef __attribute__((ext_vector_type(4))) float f32x4;
typedef __attribute__((ext_vector_type(4))) unsigned uint4v;
typedef __attribute__((ext_vector_type(4))) unsigned short us4;

#if __has_builtin(__builtin_amdgcn_exp2f)
#define EXP2F __builtin_amdgcn_exp2f
#else
#define EXP2F exp2f
#endif
#if __has_builtin(__builtin_amdgcn_rcpf)
#define RCPF __builtin_amdgcn_rcpf
#else
#define RCPF(x) (1.0f/(x))
#endif

// round-half-up bf16 (1 add; max 0.5ulp)
__device__ __forceinline__ unsigned short rnd_bf16(float f){
  return (unsigned short)((__builtin_bit_cast(unsigned, f) + 0x8000u) >> 16);
}
// pack two floats -> bf16x2 in one v_perm
__device__ __forceinline__ unsigned pk_bf16(float lo, float hi){
  unsigned a = __builtin_bit_cast(unsigned, lo) + 0x8000u;
  unsigned b = __builtin_bit_cast(unsigned, hi) + 0x8000u;
  return __builtin_amdgcn_perm(b, a, 0x07060302u);
}
__device__ __forceinline__ float bflo(unsigned u){ return __builtin_bit_cast(float, u << 16); }
__device__ __forceinline__ float bfhi(unsigned u){ return __builtin_bit_cast(float, u & 0xFFFF0000u); }

// ---------------- CSR build ----------------
__global__ __launch_bounds__(256) void k_count(const int* __restrict__ dst, int* __restrict__ cnt, int E){
  int e = blockIdx.x*256 + threadIdx.x;
  if (e < E) atomicAdd(&cnt[dst[e]], 1);
}

// 3-phase parallel scan (replaces the serial single-block scan)
__global__ __launch_bounds__(256) void k_part(const int* __restrict__ cnt, int* __restrict__ part){
  int i = blockIdx.x*256 + threadIdx.x;
  int v = cnt[i];
  #pragma unroll
  for (int off=1; off<64; off<<=1) v += __shfl_xor(v, off);
  __shared__ int red[4];
  if ((threadIdx.x & 63) == 0) red[threadIdx.x >> 6] = v;
  __syncthreads();
  if (threadIdx.x == 0) part[blockIdx.x] = red[0]+red[1]+red[2]+red[3];
}

__global__ __launch_bounds__(256) void k_scanp(int* __restrict__ part){
  __shared__ int s[256];
  int t = threadIdx.x;
  int v = part[t];
  s[t] = v;
  __syncthreads();
  for (int off=1; off<256; off<<=1){
    int u = (t >= off) ? s[t-off] : 0;
    __syncthreads();
    s[t] += u;
    __syncthreads();
  }
  part[t] = s[t] - v;   // exclusive prefix of 256 chunk sums
}

__global__ __launch_bounds__(256) void k_apply(const int* __restrict__ cnt, const int* __restrict__ part,
      int* __restrict__ csr_off, int* __restrict__ cursor, float* __restrict__ dinv){
  __shared__ int s[256];
  int b = blockIdx.x, t = threadIdx.x;
  int i = b*256 + t;
  int c = cnt[i];
  s[t] = c;
  __syncthreads();
  for (int off=1; off<256; off<<=1){
    int u = (t >= off) ? s[t-off] : 0;
    __syncthreads();
    s[t] += u;
    __syncthreads();
  }
  int o0 = part[b] + s[t] - c;
  csr_off[i] = o0;
  cursor[i] = o0;
  dinv[i] = rsqrtf(1.0f + (float)c);
  if (i == N_NODES-1) csr_off[N_NODES] = N_EDGES;
}

__global__ __launch_bounds__(256) void k_fill(const int* __restrict__ src, const int* __restrict__ dst,
      const float* __restrict__ dinv, int* __restrict__ cursor,
      int* __restrict__ csr_src, float* __restrict__ csr_w, int E){
  int e = blockIdx.x*256 + threadIdx.x;
  if (e >= E) return;
  int s = src[e], d = dst[e];
  int p = atomicAdd(&cursor[d], 1);
  csr_src[p] = s;
  csr_w[p] = dinv[s]*dinv[d];
}

// ---------------- layer-0: m = x @ W0, K=7, bf16 out ----------------
__global__ __launch_bounds__(256) void k_lin0(const float* __restrict__ x, const float* __restrict__ W0,
                                              unsigned short* __restrict__ out){
  int gid = blockIdx.x*256 + threadIdx.x;
  int l = threadIdx.x & 63;
  int n = __builtin_amdgcn_readfirstlane(gid >> 6);
  float a0 = 0.0f, a1 = 0.0f;
  #pragma unroll
  for (int k=0;k<D_IN;k++){
    float xv = x[(long)n*D_IN + k];
    float2 wv = *(const float2*)(W0 + k*H + 2*l);
    a0 = fmaf(xv, wv.x, a0); a1 = fmaf(xv, wv.y, a1);
  }
  *(unsigned*)(out + (long)n*H + 2*l) = pk_bf16(a0, a1);
}

// ---------------- bf16 MFMA GEMM: C[M,128] = A_bf16[M,128] @ B (+bias) ----------------
// outMode: 0 = bf16 row-major, 1 = fp32 row-major, 2 = bf16 transposed C^T[col*512+row]
__global__ __launch_bounds__(256) void k_gemm_mfma(const unsigned short* __restrict__ A,
      const float* __restrict__ Bsrc, const float* __restrict__ bias, void* __restrict__ Cout,
      int transB, int outMode){
  __shared__ unsigned short Bt[128][136];   // Bt[c][k], k-contiguous
  int tid = threadIdx.x;
  long rowBase = (long)blockIdx.x * 128;
  int w = tid >> 6, l = tid & 63;
  int lc = l & 15, q4 = l >> 4;

  if (transB){
    for (int i = tid; i < 4096; i += 256){
      int c = i >> 5, seg = i & 31;
      float4 v = *(const float4*)(Bsrc + (long)c*128 + seg*4);
      uint2 p; p.x = pk_bf16(v.x, v.y); p.y = pk_bf16(v.z, v.w);
      *(uint2*)&Bt[c][seg*4] = p;
    }
  } else {
    for (int i = tid; i < 4096; i += 256){
      int k = i >> 5, seg = i & 31;
      float4 v = *(const float4*)(Bsrc + (long)k*128 + seg*4);
      Bt[seg*4+0][k] = rnd_bf16(v.x); Bt[seg*4+1][k] = rnd_bf16(v.y);
      Bt[seg*4+2][k] = rnd_bf16(v.z); Bt[seg*4+3][k] = rnd_bf16(v.w);
    }
  }

  short8 af[2][4];
  #pragma unroll
  for (int rt=0;rt<2;rt++){
    long row = rowBase + w*32 + rt*16 + lc;
    #pragma unroll
    for (int kc=0;kc<4;kc++)
      af[rt][kc] = *(const short8*)(A + row*128 + kc*32 + q4*8);
  }

  f32x4 acc[2][8];
  #pragma unroll
  for (int rt=0;rt<2;rt++)
    #pragma unroll
    for (int ct=0;ct<8;ct++) acc[rt][ct] = (f32x4){0.f,0.f,0.f,0.f};

  __syncthreads();

  #pragma unroll
  for (int kc=0;kc<4;kc++){
    #pragma unroll
    for (int ct=0;ct<8;ct++){
      short8 bf = *(const short8*)&Bt[ct*16 + lc][kc*32 + q4*8];
      acc[0][ct] = __builtin_amdgcn_mfma_f32_16x16x32_bf16(af[0][kc], bf, acc[0][ct], 0,0,0);
      acc[1][ct] = __builtin_amdgcn_mfma_f32_16x16x32_bf16(af[1][kc], bf, acc[1][ct], 0,0,0);
    }
  }

  float bv[8];
  #pragma unroll
  for (int ct=0;ct<8;ct++) bv[ct] = bias ? bias[ct*16 + lc] : 0.0f;
  #pragma unroll
  for (int rt=0;rt<2;rt++){
    #pragma unroll
    for (int ct=0;ct<8;ct++){
      int col = ct*16 + lc;
      float vv[4];
      #pragma unroll
      for (int i=0;i<4;i++) vv[i] = acc[rt][ct][i] + bv[ct];
      long row0 = rowBase + w*32 + rt*16 + q4*4;
      if (outMode == 0){
        #pragma unroll
        for (int i=0;i<4;i++) ((unsigned short*)Cout)[(row0+i)*128 + col] = rnd_bf16(vv[i]);
      } else if (outMode == 1){
        #pragma unroll
        for (int i=0;i<4;i++) ((float*)Cout)[(row0+i)*128 + col] = vv[i];
      } else {
        us4 p = {rnd_bf16(vv[0]), rnd_bf16(vv[1]), rnd_bf16(vv[2]), rnd_bf16(vv[3])};
        *(us4*)((unsigned short*)Cout + (long)col*512 + row0) = p;   // C^T for V-transpose
      }
    }
  }
}

// ---------------- GCN aggregation + bias + BN + ReLU, bf16 in/out ----------------
__global__ __launch_bounds__(256) void k_agg(const unsigned short* __restrict__ m, const int* __restrict__ csr_off,
      const int* __restrict__ csr_src, const float* __restrict__ csr_w, const float* __restrict__ dinv,
      const float* __restrict__ b, const float* __restrict__ gamma, const float* __restrict__ beta,
      const float* __restrict__ mean, const float* __restrict__ var, unsigned short* __restrict__ out){
  int gt = blockIdx.x*256 + threadIdx.x;
  int lane = threadIdx.x & 63;
  int n = __builtin_amdgcn_readfirstlane(gt >> 6);
  int c = lane*2;
  float dn = dinv[n];
  float sn = dn*dn;
  unsigned ua = *(const unsigned*)(m + (long)n*H + c);
  float ax = bflo(ua)*sn, ay = bfhi(ua)*sn;
  int e0 = csr_off[n], e1 = csr_off[n+1];
  int e = e0;
  for (; e + 2 <= e1; e += 2){
    int s0 = csr_src[e],   s1 = csr_src[e+1];
    float w0 = csr_w[e],   w1 = csr_w[e+1];
    unsigned u0 = *(const unsigned*)(m + (long)s0*H + c);
    unsigned u1 = *(const unsigned*)(m + (long)s1*H + c);
    ax = fmaf(bflo(u0), w0, ax); ay = fmaf(bfhi(u0), w0, ay);
    ax = fmaf(bflo(u1), w1, ax); ay = fmaf(bfhi(u1), w1, ay);
  }
  if (e < e1){
    int s0 = csr_src[e]; float w0 = csr_w[e];
    unsigned u0 = *(const unsigned*)(m + (long)s0*H + c);
    ax = fmaf(bflo(u0), w0, ax); ay = fmaf(bfhi(u0), w0, ay);
  }
  float rx, ry;
  {
    float sc = gamma[c] * rsqrtf(var[c] + EPS);
    rx = fmaxf(sc*(ax + b[c] - mean[c]) + beta[c], 0.0f);
  }
  {
    int c1 = c+1;
    float sc = gamma[c1] * rsqrtf(var[c1] + EPS);
    ry = fmaxf(sc*(ay + b[c1] - mean[c1]) + beta[c1], 0.0f);
  }
  *(unsigned*)(out + (long)n*H + c) = pk_bf16(rx, ry);
}

// ---------------- fp32 GEMM (res projection, K=25), bf16 out ----------------
__global__ __launch_bounds__(256,2) void k_gemm(const float* __restrict__ A, const float* __restrict__ B,
      const float* __restrict__ bias, void* __restrict__ C, int K, int transB, int outBf16){
  __shared__ float Bs[128][132];
  __shared__ float As[16][128];
  int tid = threadIdx.x;
  long rowBase = (long)blockIdx.x * 128;

  if (!transB){
    for (int idx = tid; idx < 128*128; idx += 256){
      int k = idx >> 7, c = idx & 127;
      Bs[k][c] = (k < K) ? B[(long)k*128 + c] : 0.0f;
    }
  } else {
    for (int idx = tid; idx < 128*128; idx += 256){
      int c = idx >> 7, k = idx & 127;
      Bs[k][c] = (k < K) ? B[(long)c*K + k] : 0.0f;
    }
  }

  float acc[8][8];
  #pragma unroll
  for (int i=0;i<8;i++)
    #pragma unroll
    for (int j=0;j<8;j++) acc[i][j] = 0.0f;

  int rg = tid >> 4, cg = tid & 15;
  int r0 = rg*8, c0 = cg*8;
  int srow = tid >> 1, skoff = (tid & 1)*8;
  const bool fast = ((K & 15) == 0);

  for (int k0 = 0; k0 < K; k0 += 16){
    __syncthreads();
    const float* ap = A + (rowBase + srow)*K + k0 + skoff;
    if (fast){
      float4 v0 = *(const float4*)(ap);
      float4 v1 = *(const float4*)(ap + 4);
      As[skoff+0][srow] = v0.x; As[skoff+1][srow] = v0.y;
      As[skoff+2][srow] = v0.z; As[skoff+3][srow] = v0.w;
      As[skoff+4][srow] = v1.x; As[skoff+5][srow] = v1.y;
      As[skoff+6][srow] = v1.z; As[skoff+7][srow] = v1.w;
    } else {
      #pragma unroll
      for (int j=0;j<8;j++){
        int kk = k0 + skoff + j;
        As[skoff+j][srow] = (kk < K) ? ap[j] : 0.0f;
      }
    }
    __syncthreads();
    #pragma unroll
    for (int k=0;k<16;k++){
      float4 a0 = *(const float4*)(&As[k][r0]);
      float4 a1 = *(const float4*)(&As[k][r0+4]);
      float4 b0 = *(const float4*)(&Bs[k0+k][c0]);
      float4 b1 = *(const float4*)(&Bs[k0+k][c0+4]);
      float a[8] = {a0.x,a0.y,a0.z,a0.w,a1.x,a1.y,a1.z,a1.w};
      float b[8] = {b0.x,b0.y,b0.z,b0.w,b1.x,b1.y,b1.z,b1.w};
      #pragma unroll
      for (int i=0;i<8;i++)
        #pragma unroll
        for (int j=0;j<8;j++)
          acc[i][j] = fmaf(a[i], b[j], acc[i][j]);
    }
  }

  #pragma unroll
  for (int i=0;i<8;i++){
    float o[8];
    #pragma unroll
    for (int j=0;j<8;j++) o[j] = acc[i][j] + (bias ? bias[c0+j] : 0.0f);
    long row = rowBase + r0 + i;
    if (outBf16){
      uint4v p;
      p.x = pk_bf16(o[0],o[1]); p.y = pk_bf16(o[2],o[3]);
      p.z = pk_bf16(o[4],o[5]); p.w = pk_bf16(o[6],o[7]);
      *(uint4v*)((unsigned short*)C + row*128 + c0) = p;
    } else {
      float* cp = (float*)C + row*128 + c0;
      *(float4*)cp = (float4){o[0],o[1],o[2],o[3]};
      *(float4*)(cp+4) = (float4){o[4],o[5],o[6],o[7]};
    }
  }
}

// ---------------- fused q-proj + flash cross-attention, zero LDS ----------------
// Operand-swapped: S^T = MFMA(A=K, B=Q^T), o^T = MFMA(A=V^T, B=P^T).
// C-layout -> B-layout turn is a cross-quad exchange at fixed lc:
// target quad qt pulls packed dwords from quads (qt&1)*2 and (qt&1)*2+1,
// selecting tile-pair (qt>>1). 8 bpermutes + 4 selects, no LDS, no barriers.
__global__ __launch_bounds__(256,4) void k_attn(const unsigned short* __restrict__ hb,
      const float* __restrict__ inW, const float* __restrict__ inb,
      const unsigned short* __restrict__ Kbf, const unsigned short* __restrict__ Vt,
      unsigned short* __restrict__ obuf){
  int tid = threadIdx.x;
  int h = blockIdx.y;
  int w = tid >> 6, l = tid & 63;
  int lc = l & 15, q4 = l >> 4;
  long nb = (long)blockIdx.x*256 + w*64;
  const float scale = 0.25503489f;   // log2(e)/sqrt(32)

  int srcA = lc + (q4 & 1)*32;
  int srcB = srcA + 16;
  bool hi = (q4 >> 1) != 0;

  // Wq A-frags: A[m=dim_local=lc][k=hid]
  short8 wq[2][4];
  #pragma unroll
  for (int t=0;t<2;t++){
    const float* wp0 = inW + (long)(h*32 + t*16 + lc)*128 + q4*8;
    #pragma unroll
    for (int kc=0;kc<4;kc++){
      const float* wp = wp0 + kc*32;
      float4 x0 = *(const float4*)wp;
      float4 x1 = *(const float4*)(wp+4);
      uint4v p; p.x = pk_bf16(x0.x,x0.y); p.y = pk_bf16(x0.z,x0.w);
      p.z = pk_bf16(x1.x,x1.y); p.w = pk_bf16(x1.z,x1.w);
      wq[t][kc] = __builtin_bit_cast(short8, p);
    }
  }
  float bq[2][4];
  #pragma unroll
  for (int t=0;t<2;t++)
    #pragma unroll
    for (int i=0;i<4;i++) bq[t][i] = inb[h*32 + t*16 + q4*4 + i];

  // q^T = Wq @ h^T per 16-node tile, then turn C-layout -> B-frag
  short8 qB[4];
  #pragma unroll
  for (int nt=0;nt<4;nt++){
    short8 hf[4];
    #pragma unroll
    for (int kc=0;kc<4;kc++)
      hf[kc] = *(const short8*)(hb + (nb + nt*16 + lc)*128 + kc*32 + q4*8);
    f32x4 qa0 = (f32x4){0.f,0.f,0.f,0.f};
    f32x4 qa1 = (f32x4){0.f,0.f,0.f,0.f};
    #pragma unroll
    for (int kc=0;kc<4;kc++){
      qa0 = __builtin_amdgcn_mfma_f32_16x16x32_bf16(wq[0][kc], hf[kc], qa0, 0,0,0);
      qa1 = __builtin_amdgcn_mfma_f32_16x16x32_bf16(wq[1][kc], hf[kc], qa1, 0,0,0);
    }
    unsigned P0 = pk_bf16((qa0[0]+bq[0][0])*scale, (qa0[1]+bq[0][1])*scale);
    unsigned P1 = pk_bf16((qa0[2]+bq[0][2])*scale, (qa0[3]+bq[0][3])*scale);
    unsigned P2 = pk_bf16((qa1[0]+bq[1][0])*scale, (qa1[1]+bq[1][1])*scale);
    unsigned P3 = pk_bf16((qa1[2]+bq[1][2])*scale, (qa1[3]+bq[1][3])*scale);
    unsigned x0 = __shfl(P0, srcA), x1 = __shfl(P1, srcA), x2 = __shfl(P2, srcA), x3 = __shfl(P3, srcA);
    unsigned y0 = __shfl(P0, srcB), y1 = __shfl(P1, srcB), y2 = __shfl(P2, srcB), y3 = __shfl(P3, srcB);
    uint4v bp; bp.x = hi?x2:x0; bp.y = hi?x3:x1; bp.z = hi?y2:y0; bp.w = hi?y3:y1;
    qB[nt] = __builtin_bit_cast(short8, bp);
  }

  f32x4 oA[4], oB[4];
  float ps[4];
  #pragma unroll
  for (int nt=0;nt<4;nt++){
    oA[nt] = (f32x4){0.f,0.f,0.f,0.f};
    oB[nt] = (f32x4){0.f,0.f,0.f,0.f};
    ps[nt] = 0.0f;
  }

  const unsigned short* Kp  = Kbf + (long)lc*128 + h*32 + q4*8;
  const unsigned short* VpA = Vt + (long)(h*32      + lc)*512 + q4*8;
  const unsigned short* VpB = Vt + (long)(h*32 + 16 + lc)*512 + q4*8;

  for (int ch = 0; ch < 16; ch++){
    short8 kfA = *(const short8*)(Kp + (long)(ch*32)*128);
    short8 kfB = *(const short8*)(Kp + (long)(ch*32+16)*128);
    short8 vfA = *(const short8*)(VpA + ch*32);
    short8 vfB = *(const short8*)(VpB + ch*32);
    #pragma unroll
    for (int nt=0;nt<4;nt++){
      f32x4 z = {0.f,0.f,0.f,0.f};
      f32x4 sa = __builtin_amdgcn_mfma_f32_16x16x32_bf16(kfA, qB[nt], z, 0,0,0);
      f32x4 sb = __builtin_amdgcn_mfma_f32_16x16x32_bf16(kfB, qB[nt], z, 0,0,0);
      float ea0 = EXP2F(sa[0]), ea1 = EXP2F(sa[1]), ea2 = EXP2F(sa[2]), ea3 = EXP2F(sa[3]);
      float eb0 = EXP2F(sb[0]), eb1 = EXP2F(sb[1]), eb2 = EXP2F(sb[2]), eb3 = EXP2F(sb[3]);
      ps[nt] += ((ea0+ea1)+(ea2+ea3)) + ((eb0+eb1)+(eb2+eb3));
      unsigned P0 = pk_bf16(ea0, ea1), P1 = pk_bf16(ea2, ea3);
      unsigned P2 = pk_bf16(eb0, eb1), P3 = pk_bf16(eb2, eb3);
      unsigned x0 = __shfl(P0, srcA), x1 = __shfl(P1, srcA), x2 = __shfl(P2, srcA), x3 = __shfl(P3, srcA);
      unsigned y0 = __shfl(P0, srcB), y1 = __shfl(P1, srcB), y2 = __shfl(P2, srcB), y3 = __shfl(P3, srcB);
      uint4v bp; bp.x = hi?x2:x0; bp.y = hi?x3:x1; bp.z = hi?y2:y0; bp.w = hi?y3:y1;
      short8 pf = __builtin_bit_cast(short8, bp);
      oA[nt] = __builtin_amdgcn_mfma_f32_16x16x32_bf16(vfA, pf, oA[nt], 0,0,0);
      oB[nt] = __builtin_amdgcn_mfma_f32_16x16x32_bf16(vfB, pf, oB[nt], 0,0,0);
    }
  }

  #pragma unroll
  for (int nt=0;nt<4;nt++){
    float s = ps[nt];
    s += __shfl_xor(s, 16);
    s += __shfl_xor(s, 32);
    float inv = RCPF(s);
    long node = nb + nt*16 + lc;
    us4 a = { rnd_bf16(oA[nt][0]*inv), rnd_bf16(oA[nt][1]*inv),
              rnd_bf16(oA[nt][2]*inv), rnd_bf16(oA[nt][3]*inv) };
    us4 b = { rnd_bf16(oB[nt][0]*inv), rnd_bf16(oB[nt][1]*inv),
              rnd_bf16(oB[nt][2]*inv), rnd_bf16(oB[nt][3]*inv) };
    *(us4*)(obuf + node*128 + h*32 + q4*4) = a;
    *(us4*)(obuf + node*128 + h*32 + 16 + q4*4) = b;
  }
}

// ---------------- fused out-proj + mean-pool + classifier: block = 128 nodes = 2 graphs ----------------
__global__ __launch_bounds__(256) void k_gemm_out(const unsigned short* __restrict__ A,
      const float* __restrict__ Bsrc, const float* __restrict__ bias,
      const float* __restrict__ W1, const float* __restrict__ b1,
      const float* __restrict__ W2, const float* __restrict__ b2, float* __restrict__ out){
  __shared__ unsigned short Bt[128][136];
  __shared__ float pools[4][128];
  __shared__ float pooled[2][128];
  int tid = threadIdx.x;
  long rowBase = (long)blockIdx.x * 128;
  int w = tid >> 6, l = tid & 63;
  int lc = l & 15, q4 = l >> 4;

  for (int i = tid; i < 4096; i += 256){
    int c = i >> 5, seg = i & 31;
    float4 v = *(const float4*)(Bsrc + (long)c*128 + seg*4);
    uint2 p; p.x = pk_bf16(v.x, v.y); p.y = pk_bf16(v.z, v.w);
    *(uint2*)&Bt[c][seg*4] = p;
  }

  short8 af[2][4];
  #pragma unroll
  for (int rt=0;rt<2;rt++){
    long row = rowBase + w*32 + rt*16 + lc;
    #pragma unroll
    for (int kc=0;kc<4;kc++)
      af[rt][kc] = *(const short8*)(A + row*128 + kc*32 + q4*8);
  }

  f32x4 acc[2][8];
  #pragma unroll
  for (int rt=0;rt<2;rt++)
    #pragma unroll
    for (int ct=0;ct<8;ct++) acc[rt][ct] = (f32x4){0.f,0.f,0.f,0.f};

  __syncthreads();

  #pragma unroll
  for (int kc=0;kc<4;kc++){
    #pragma unroll
    for (int ct=0;ct<8;ct++){
      short8 bf = *(const short8*)&Bt[ct*16 + lc][kc*32 + q4*8];
      acc[0][ct] = __builtin_amdgcn_mfma_f32_16x16x32_bf16(af[0][kc], bf, acc[0][ct], 0,0,0);
      acc[1][ct] = __builtin_amdgcn_mfma_f32_16x16x32_bf16(af[1][kc], bf, acc[1][ct], 0,0,0);
    }
  }

  #pragma unroll
  for (int ct=0;ct<8;ct++){
    float ps = acc[0][ct][0]+acc[0][ct][1]+acc[0][ct][2]+acc[0][ct][3]
             + acc[1][ct][0]+acc[1][ct][1]+acc[1][ct][2]+acc[1][ct][3];
    ps += __shfl_xor(ps, 16);
    ps += __shfl_xor(ps, 32);
    if (q4 == 0) pools[w][ct*16 + lc] = ps;
  }
  __syncthreads();

  if (tid < 128){
    int c = tid;
    pooled[0][c] = (pools[0][c] + pools[1][c]) * (1.0f/64.0f) + bias[c];
    pooled[1][c] = (pools[2][c] + pools[3][c]) * (1.0f/64.0f) + bias[c];
  }
  __syncthreads();

  if (tid < 128){
    int g = tid >> 6, tp = tid & 63;
    float hh = b1[tp];
    for (int c=0;c<128;c++) hh = fmaf(pooled[g][c], W1[c*64 + tp], hh);
    hh = fmaxf(hh, 0.0f);
    float v = hh * W2[tp];
    #pragma unroll
    for (int off=32; off>0; off>>=1) v += __shfl_down(v, off);
    if (tp == 0) out[blockIdx.x*2 + g] = v + b2[0];
  }
}

extern "C" void kernel_launch(void* const* d_in, const int* in_sizes, int n_in,
                              void* d_out, int out_size, void* d_ws, size_t ws_size,
                              hipStream_t stream){
  const float* x     = (const float*)d_in[0];
  const int*   ei    = (const int*)d_in[1];
  const float* perres= (const float*)d_in[3];
  const float* W0 = (const float*)d_in[4];
  const float* b0 = (const float*)d_in[5];
  const float* W1 = (const float*)d_in[6];  const float* b1 = (const float*)d_in[7];
  const float* W2 = (const float*)d_in[8];  const float* b2 = (const float*)d_in[9];
  const float* bng = (const float*)d_in[10]; const float* bnb = (const float*)d_in[11];
  const float* bnm = (const float*)d_in[12]; const float* bnv = (const float*)d_in[13];
  const float* resW = (const float*)d_in[14]; const float* resb = (const float*)d_in[15];
  const float* inW  = (const float*)d_in[16]; const float* inb  = (const float*)d_in[17];
  const float* outW = (const float*)d_in[18]; const float* outb = (const float*)d_in[19];
  const float* cW1 = (const float*)d_in[20]; const float* cb1 = (const float*)d_in[21];
  const float* cW2 = (const float*)d_in[22]; const float* cb2 = (const float*)d_in[23];
  float* out = (float*)d_out;

  char* ws = (char*)d_ws;
  size_t off = 0;
  auto alloc = [&](size_t bytes) -> char* {
    char* p = ws + off;
    off += (bytes + 255) & ~(size_t)255;
    return p;
  };
  float* dinv    = (float*)alloc((size_t)N_NODES*4);
  int*   cnt     = (int*)  alloc((size_t)N_NODES*4);
  int*   cursor  = (int*)  alloc((size_t)N_NODES*4);
  int*   csr_off = (int*)  alloc((size_t)(N_NODES+1)*4);
  int*   csr_src = (int*)  alloc((size_t)N_EDGES*4);
  float* csr_w   = (float*)alloc((size_t)N_EDGES*4);
  int*   part    = (int*)  alloc((size_t)256*4);
  unsigned short* mb  = (unsigned short*)alloc((size_t)N_NODES*H*2);  // bf16: m / o
  unsigned short* hb  = (unsigned short*)alloc((size_t)N_NODES*H*2);  // bf16: h
  unsigned short* resbuf = (unsigned short*)alloc((size_t)R_RES*H*2); // bf16
  unsigned short* Kbf = (unsigned short*)alloc((size_t)R_RES*H*2);    // bf16 K [512][128]
  unsigned short* Vtb = (unsigned short*)alloc((size_t)H*R_RES*2);    // bf16 V^T [128][512]
  if (off > ws_size) return;

  const int* srcI = ei;
  const int* dstI = ei + N_EDGES;

  // CSR build (parallel 3-phase scan)
  hipMemsetAsync(cnt, 0, (size_t)N_NODES*4, stream);
  k_count<<<N_EDGES/256, 256, 0, stream>>>(dstI, cnt, N_EDGES);
  k_part <<<N_NODES/256, 256, 0, stream>>>(cnt, part);
  k_scanp<<<1, 256, 0, stream>>>(part);
  k_apply<<<N_NODES/256, 256, 0, stream>>>(cnt, part, csr_off, cursor, dinv);
  k_fill <<<N_EDGES/256, 256, 0, stream>>>(srcI, dstI, dinv, cursor, csr_src, csr_w, N_EDGES);

  const int NB = N_NODES/128;
  // GCN: layer 0 (K=7 VALU), layers 1/2 via MFMA
  k_lin0<<<N_NODES/4, 256, 0, stream>>>(x, W0, mb);
  k_agg<<<N_NODES/4, 256, 0, stream>>>(mb, csr_off, csr_src, csr_w, dinv, b0, bng,     bnb,     bnm,     bnv,     hb);
  k_gemm_mfma<<<NB, 256, 0, stream>>>(hb, W1, nullptr, mb, 0, 0);
  k_agg<<<N_NODES/4, 256, 0, stream>>>(mb, csr_off, csr_src, csr_w, dinv, b1, bng+128, bnb+128, bnm+128, bnv+128, hb);
  k_gemm_mfma<<<NB, 256, 0, stream>>>(hb, W2, nullptr, mb, 0, 0);
  k_agg<<<N_NODES/4, 256, 0, stream>>>(mb, csr_off, csr_src, csr_w, dinv, b2, bng+256, bnb+256, bnm+256, bnv+256, hb);

  // residue chain: res-proj (K=25, fp32 math, bf16 out); K bf16 row-major; V bf16 transposed
  k_gemm<<<R_RES/128, 256, 0, stream>>>(perres, resW, resb, resbuf, 25, 0, 1);
  k_gemm_mfma<<<R_RES/128, 256, 0, stream>>>(resbuf, inW + 128*128, inb + 128, Kbf, 1, 0);
  k_gemm_mfma<<<R_RES/128, 256, 0, stream>>>(resbuf, inW + 256*128, inb + 256, Vtb, 1, 2);

  // fused q-proj + attention (o -> mb), zero-LDS
  dim3 agrid(N_NODES/256, NH);
  k_attn<<<agrid, 256, 0, stream>>>(hb, inW, inb, Kbf, Vtb, mb);

  // fused out-proj + mean pool + classifier
  k_gemm_out<<<NB, 256, 0, stream>>>(mb, outW, outb, cW1, cb1, cW2, cb2, out);
}